// Round 11
// baseline (171.844 us; speedup 1.0000x reference)
//
#include <hip/hip_runtime.h>
#include <cstddef>

#define EPS1f 1e-6f
#define WDf   1e-5f

constexpr int Bsz = 512, Csz = 500, Zsz = 64, Ssz = 100;

typedef short bf16x8 __attribute__((ext_vector_type(8)));
typedef float f32x4 __attribute__((ext_vector_type(4)));

__device__ inline short f2bf(float f) {
  union { float f; unsigned u; } v; v.f = f;
  unsigned r = (v.u + 0x7fffu + ((v.u >> 16) & 1u)) >> 16;   // RNE
  return (short)r;
}

// log( Phi(t)*(1-eps) + eps/2 )  via A&S 7.1.26 erfc approx (|err|<=1.5e-7)
__device__ inline float log_probit(float t) {
  const float u = t * -0.70710678118654752f;
  const float au = fabsf(u);
  const float s = 1.f / fmaf(0.3275911f, au, 1.f);
  float p = fmaf(1.061405429f, s, -1.453152027f);
  p = fmaf(p, s, 1.421413741f);
  p = fmaf(p, s, -0.284496736f);
  p = fmaf(p, s, 0.254829592f);
  p = p * s;
  const float e = __expf(-au * au);
  const float f = p * e;
  const float erfc_u = (u < 0.f) ? (2.f - f) : f;
  const float E = fmaf(0.5f * erfc_u, 1.f - EPS1f, 0.5f * EPS1f);
  return __logf(E);
}

__device__ inline float block_reduce_sum(float v, float* red) {
  #pragma unroll
  for (int off = 32; off > 0; off >>= 1) v += __shfl_down(v, off, 64);
  const int lane = threadIdx.x & 63, wid = threadIdx.x >> 6;
  if (lane == 0) red[wid] = v;
  __syncthreads();
  float r = 0.f;
  if (threadIdx.x == 0) {
    const int nw = blockDim.x >> 6;
    for (int i = 0; i < nw; ++i) r += red[i];
  }
  __syncthreads();
  return r;   // valid in thread 0 only
}

// ---------------- inter-block phase barrier (small co-resident grids only) ----------------
__device__ __forceinline__ void phase_arrive(unsigned* cnt) {
  __threadfence();            // each thread releases its own stores (device scope)
  __syncthreads();            // all fences in the block complete
  if (threadIdx.x == 0) atomicAdd(cnt, 1u);
}
__device__ __forceinline__ void phase_wait(unsigned* cnt, unsigned target) {
  if (threadIdx.x == 0) {
    while (__hip_atomic_load(cnt, __ATOMIC_ACQUIRE, __HIP_MEMORY_SCOPE_AGENT) < target)
      __builtin_amdgcn_s_sleep(1);
  }
  __syncthreads();
}

// ---------------- 32x32 double-buffered GEMM body ----------------
__device__ __forceinline__ void gemm32_body(
    const float* __restrict__ A, const float* __restrict__ W,
    const float* __restrict__ bias, float* __restrict__ out,
    int M, int N, int K, int bn0, int bm0, float* As_, float* Ws_, bool relu) {
  const int tid = threadIdx.x;
  const int bn = bn0 * 32, bm = bm0 * 32;
  const int sm = tid >> 3, sk4 = (tid & 7) * 4;
  const int sk = tid >> 3, sn4 = (tid & 7) * 4;
  const int tn = tid & 15, tm = tid >> 4;
  #define AS_(b, k, m) As_[(b) * 1152 + (k) * 36 + (m)]
  #define WS_(b, k, n) Ws_[(b) * 1152 + (k) * 36 + (n)]
  auto loadW = [&](int kt, float4& wv) {
    const float* wrow = W + (size_t)(kt + sk) * N;
    const int nn = bn + sn4;
    if (nn + 3 < N) wv = *reinterpret_cast<const float4*>(wrow + nn);
    else {
      wv.x = (nn + 0 < N) ? wrow[nn + 0] : 0.f;
      wv.y = (nn + 1 < N) ? wrow[nn + 1] : 0.f;
      wv.z = (nn + 2 < N) ? wrow[nn + 2] : 0.f;
      wv.w = (nn + 3 < N) ? wrow[nn + 3] : 0.f;
    }
  };
  {
    float4 av = *reinterpret_cast<const float4*>(A + (size_t)(bm + sm) * K + sk4);
    float4 wv; loadW(0, wv);
    AS_(0, sk4 + 0, sm) = av.x; AS_(0, sk4 + 1, sm) = av.y;
    AS_(0, sk4 + 2, sm) = av.z; AS_(0, sk4 + 3, sm) = av.w;
    *reinterpret_cast<float4*>(&WS_(0, sk, sn4)) = wv;
  }
  __syncthreads();
  float acc[2][2] = {};
  int pb = 0;
  for (int kt = 0; kt < K; kt += 32) {
    const bool more = (kt + 32) < K;
    float4 av2, wv2;
    if (more) {
      av2 = *reinterpret_cast<const float4*>(A + (size_t)(bm + sm) * K + kt + 32 + sk4);
      loadW(kt + 32, wv2);
    }
    #pragma unroll
    for (int k = 0; k < 32; ++k) {
      const float2 a = *reinterpret_cast<const float2*>(&AS_(pb, k, tm * 2));
      const float2 w = *reinterpret_cast<const float2*>(&WS_(pb, k, tn * 2));
      acc[0][0] = fmaf(a.x, w.x, acc[0][0]);
      acc[0][1] = fmaf(a.x, w.y, acc[0][1]);
      acc[1][0] = fmaf(a.y, w.x, acc[1][0]);
      acc[1][1] = fmaf(a.y, w.y, acc[1][1]);
    }
    if (more) {
      const int nb = pb ^ 1;
      AS_(nb, sk4 + 0, sm) = av2.x; AS_(nb, sk4 + 1, sm) = av2.y;
      AS_(nb, sk4 + 2, sm) = av2.z; AS_(nb, sk4 + 3, sm) = av2.w;
      *reinterpret_cast<float4*>(&WS_(nb, sk, sn4)) = wv2;
      __syncthreads();
      pb = nb;
    }
  }
  #pragma unroll
  for (int j = 0; j < 2; ++j) {
    const int n = bn + tn * 2 + j;
    if (n >= N) continue;
    const float bv = bias[n];
    #pragma unroll
    for (int i = 0; i < 2; ++i) {
      const int m = bm + tm * 2 + i;
      float v = acc[i][j] + bv;
      if (relu) v = fmaxf(v, 0.f);
      out[(size_t)m * N + n] = v;
    }
  }
  #undef AS_
  #undef WS_
}

// ---------------- MU GEMM body: -> indiv_prob, CE partials, rmuB/yB ----------------
__device__ __forceinline__ void mu_body(
    const float* __restrict__ A, const float* __restrict__ W,
    const float* __restrict__ bias, const float* __restrict__ Y,
    const float* __restrict__ sqrtcov,
    float* __restrict__ out_prob, float* __restrict__ rmuB, float* __restrict__ yB,
    float* __restrict__ ce_part, int bn0, int bm0, float* As_, float* Ws_) {
  const int N = Csz, K = 256;
  const int tid = threadIdx.x;
  const int bn = bn0 * 32, bm = bm0 * 32;
  const int sm = tid >> 3, sk4 = (tid & 7) * 4;
  const int sk = tid >> 3, sn4 = (tid & 7) * 4;
  const int tn = tid & 15, tm = tid >> 4;
  #define AS_(b, k, m) As_[(b) * 1152 + (k) * 36 + (m)]
  #define WS_(b, k, n) Ws_[(b) * 1152 + (k) * 36 + (n)]
  auto loadW = [&](int kt, float4& wv) {
    const float* wrow = W + (size_t)(kt + sk) * N;
    const int nn = bn + sn4;
    if (nn + 3 < N) wv = *reinterpret_cast<const float4*>(wrow + nn);
    else {
      wv.x = (nn + 0 < N) ? wrow[nn + 0] : 0.f;
      wv.y = (nn + 1 < N) ? wrow[nn + 1] : 0.f;
      wv.z = (nn + 2 < N) ? wrow[nn + 2] : 0.f;
      wv.w = (nn + 3 < N) ? wrow[nn + 3] : 0.f;
    }
  };
  {
    float4 av = *reinterpret_cast<const float4*>(A + (size_t)(bm + sm) * K + sk4);
    float4 wv; loadW(0, wv);
    AS_(0, sk4 + 0, sm) = av.x; AS_(0, sk4 + 1, sm) = av.y;
    AS_(0, sk4 + 2, sm) = av.z; AS_(0, sk4 + 3, sm) = av.w;
    *reinterpret_cast<float4*>(&WS_(0, sk, sn4)) = wv;
  }
  __syncthreads();
  float acc[2][2] = {};
  int pb = 0;
  for (int kt = 0; kt < K; kt += 32) {
    const bool more = (kt + 32) < K;
    float4 av2, wv2;
    if (more) {
      av2 = *reinterpret_cast<const float4*>(A + (size_t)(bm + sm) * K + kt + 32 + sk4);
      loadW(kt + 32, wv2);
    }
    #pragma unroll
    for (int k = 0; k < 32; ++k) {
      const float2 aa = *reinterpret_cast<const float2*>(&AS_(pb, k, tm * 2));
      const float2 ww = *reinterpret_cast<const float2*>(&WS_(pb, k, tn * 2));
      acc[0][0] = fmaf(aa.x, ww.x, acc[0][0]);
      acc[0][1] = fmaf(aa.x, ww.y, acc[0][1]);
      acc[1][0] = fmaf(aa.y, ww.x, acc[1][0]);
      acc[1][1] = fmaf(aa.y, ww.y, acc[1][1]);
    }
    if (more) {
      const int nb = pb ^ 1;
      AS_(nb, sk4 + 0, sm) = av2.x; AS_(nb, sk4 + 1, sm) = av2.y;
      AS_(nb, sk4 + 2, sm) = av2.z; AS_(nb, sk4 + 3, sm) = av2.w;
      *reinterpret_cast<float4*>(&WS_(nb, sk, sn4)) = wv2;
      __syncthreads();
      pb = nb;
    }
  }
  float ce2[2] = {0.f, 0.f};
  #pragma unroll
  for (int i = 0; i < 2; ++i) {
    const int m = bm + tm * 2 + i;
    #pragma unroll
    for (int j = 0; j < 2; ++j) {
      const int n = bn + tn * 2 + j;
      if (n < N) {
        const float v = acc[i][j] + bias[n];
        const float sp = 1.f / (1.f + __expf(-1.70169f * v));
        const float p = fmaf(sp, 1.f - EPS1f, 0.5f * EPS1f);
        const float q = fmaf(1.f - sp, 1.f - EPS1f, 0.5f * EPS1f);
        const float y = Y[(size_t)m * N + n];
        out_prob[(size_t)m * N + n] = p;
        ce2[i] += __logf((y > 0.5f) ? p : q);
        rmuB[(size_t)m * 512 + n] = v * sqrtcov[n];
        yB[(size_t)m * 512 + n] = y;
      }
    }
  }
  #pragma unroll
  for (int off = 1; off < 16; off <<= 1) {
    ce2[0] += __shfl_xor(ce2[0], off, 64);
    ce2[1] += __shfl_xor(ce2[1], off, 64);
  }
  if (tn == 0) {
    const int m0 = bm + tm * 2;
    ce_part[(size_t)bn0 * Bsz + m0] = ce2[0];
    ce_part[(size_t)bn0 * Bsz + m0 + 1] = ce2[1];
  }
  #undef AS_
  #undef WS_
}

// ---------------- PREP: nprep(0-799) | rprep(800-807) | l2(808-871) | gemm1(872-935) ----------------
__global__ __launch_bounds__(256) void prep_kernel(
    const float* __restrict__ noise, short* __restrict__ nfB,
    const float* __restrict__ R, short* __restrict__ Rb, float* __restrict__ sqrtcov,
    const float* __restrict__ X, const float* __restrict__ W1,
    const float* __restrict__ b1, float* __restrict__ h1,
    const float* __restrict__ W2, const float* __restrict__ W3,
    const float* __restrict__ Wmu, float* __restrict__ l2_part,
    unsigned* __restrict__ cnt) {
  __shared__ float smem[2304 * 2];
  const int blk = blockIdx.x;
  const int tid = threadIdx.x;
  if (blk == 0 && tid < 8) cnt[tid] = 0;   // reset phase counters for this call
  if (blk < 800) {
    const int g = blk * 256 + tid;       // 204800
    const int s = g >> 11;
    const int r = g & 2047;
    const int bt = r >> 6;
    const int ln = r & 63;
    const int cl = ln & 15, grp = ln >> 4;
    const float* src = noise + ((size_t)(s * 512 + bt * 16 + cl) * 64 + grp * 8);
    const float4 a = *reinterpret_cast<const float4*>(src);
    const float4 b = *reinterpret_cast<const float4*>(src + 4);
    const float4 c = *reinterpret_cast<const float4*>(src + 32);
    const float4 d = *reinterpret_cast<const float4*>(src + 36);
    bf16x8* dst = reinterpret_cast<bf16x8*>(nfB);
    const int u = (s * 32 + bt) * 128 + ln;
    dst[u]      = bf16x8{ f2bf(a.x), f2bf(a.y), f2bf(a.z), f2bf(a.w),
                          f2bf(b.x), f2bf(b.y), f2bf(b.z), f2bf(b.w) };
    dst[u + 64] = bf16x8{ f2bf(c.x), f2bf(c.y), f2bf(c.z), f2bf(c.w),
                          f2bf(d.x), f2bf(d.y), f2bf(d.z), f2bf(d.w) };
  } else if (blk < 808) {
    const int idx = (blk - 800) * 256 + tid;   // 0..2047
    const int c = idx >> 2;
    const int zq = (idx & 3) * 16;
    const bool cv = c < Csz;
    const float* src = R + (size_t)c * Zsz + zq;
    float4 r0, r1, r2, r3;
    if (cv) {
      r0 = *reinterpret_cast<const float4*>(src);
      r1 = *reinterpret_cast<const float4*>(src + 4);
      r2 = *reinterpret_cast<const float4*>(src + 8);
      r3 = *reinterpret_cast<const float4*>(src + 12);
    } else {
      r0 = r1 = r2 = r3 = make_float4(0.f, 0.f, 0.f, 0.f);
    }
    float ss = 0.f;
    ss = fmaf(r0.x, r0.x, ss); ss = fmaf(r0.y, r0.y, ss);
    ss = fmaf(r0.z, r0.z, ss); ss = fmaf(r0.w, r0.w, ss);
    ss = fmaf(r1.x, r1.x, ss); ss = fmaf(r1.y, r1.y, ss);
    ss = fmaf(r1.z, r1.z, ss); ss = fmaf(r1.w, r1.w, ss);
    ss = fmaf(r2.x, r2.x, ss); ss = fmaf(r2.y, r2.y, ss);
    ss = fmaf(r2.z, r2.z, ss); ss = fmaf(r2.w, r2.w, ss);
    ss = fmaf(r3.x, r3.x, ss); ss = fmaf(r3.y, r3.y, ss);
    ss = fmaf(r3.z, r3.z, ss); ss = fmaf(r3.w, r3.w, ss);
    short* dst = Rb + (size_t)c * Zsz + zq;
    *reinterpret_cast<bf16x8*>(dst) =
        bf16x8{ f2bf(r0.x), f2bf(r0.y), f2bf(r0.z), f2bf(r0.w),
                f2bf(r1.x), f2bf(r1.y), f2bf(r1.z), f2bf(r1.w) };
    *reinterpret_cast<bf16x8*>(dst + 8) =
        bf16x8{ f2bf(r2.x), f2bf(r2.y), f2bf(r2.z), f2bf(r2.w),
                f2bf(r3.x), f2bf(r3.y), f2bf(r3.z), f2bf(r3.w) };
    ss += __shfl_xor(ss, 1, 64);
    ss += __shfl_xor(ss, 2, 64);
    if ((idx & 3) == 0 && cv) sqrtcov[c] = sqrtf(1.f + ss);
  } else if (blk < 872) {
    const int bid = blk - 808;
    const int gid = bid * 256 + tid;
    const int stride = 64 * 256;
    float s = 0.f;
    for (int i = gid; i < 65536; i += stride) { float v = W1[i]; s = fmaf(v, v, s); }
    for (int i = gid; i < 32768; i += stride) { float v = W2[i]; s = fmaf(v, v, s); }
    for (int i = gid; i < 65536; i += stride) { float v = W3[i]; s = fmaf(v, v, s); }
    for (int i = gid; i < 128000; i += stride) { float v = Wmu[i]; s = fmaf(v, v, s); }
    const float tot = block_reduce_sum(s, smem);
    if (tid == 0) l2_part[bid] = tot;
  } else {
    const int idx = blk - 872;                  // 0..63
    gemm32_body(X, W1, b1, h1, 512, 128, 512, idx & 3, idx >> 2,
                smem, smem + 2304, true);
  }
}

// ---------------- TRUNK: gemm2 -> bar -> gemm3 -> bar -> gemm_mu (256 blocks) ----------------
__global__ __launch_bounds__(256) void trunk_kernel(
    const float* __restrict__ h1, const float* __restrict__ W2, const float* __restrict__ b2,
    float* __restrict__ h2, const float* __restrict__ W3, const float* __restrict__ b3,
    float* __restrict__ feat, const float* __restrict__ Wmu, const float* __restrict__ bmu,
    const float* __restrict__ Y, const float* __restrict__ sqrtcov,
    float* __restrict__ out_prob, float* __restrict__ rmuB, float* __restrict__ yB,
    float* __restrict__ ce_part, unsigned* __restrict__ cnt) {
  __shared__ float smem[2304 * 2];
  const int bid = (int)blockIdx.x;
  // phase 1: gemm2 (128 units)
  if (bid < 128)
    gemm32_body(h1, W2, b2, h2, 512, 256, 128, bid & 7, bid >> 3, smem, smem + 2304, true);
  phase_arrive(cnt + 0);
  phase_wait(cnt + 0, 256);
  // phase 2: gemm3 (128 units)
  if (bid < 128)
    gemm32_body(h2, W3, b3, feat, 512, 256, 256, bid & 7, bid >> 3, smem, smem + 2304, true);
  phase_arrive(cnt + 1);
  phase_wait(cnt + 1, 256);
  // phase 3: mu GEMM + epilogue (256 units)
  mu_body(feat, Wmu, bmu, Y, sqrtcov, out_prob, rmuB, yB, ce_part,
          bid & 15, bid >> 4, smem, smem + 2304);
}

// ---------------- HOT: s-inner MFMA + probit log-likelihood, 2-way s ILP ----------------
__global__ __launch_bounds__(256, 5) void logprob_s(
    const short* __restrict__ nfB, const short* __restrict__ Rb,
    const float* __restrict__ rmuB, const float* __restrict__ yB,
    float* __restrict__ lp_part) {
  const int blk = blockIdx.x;          // sg*256 + ctg*32 + bt
  const int bt = blk & 31;
  const int ctg = (blk >> 5) & 7;
  const int sg = blk >> 8;             // 0..9
  const int wid = threadIdx.x >> 6;
  const int lane = threadIdx.x & 63;
  const int cl = lane & 15, grp = lane >> 4;
  const int ct = ctg * 4 + wid;
  const int c0 = ct * 16, b0 = bt * 16;

  const bf16x8 Rf0 = *reinterpret_cast<const bf16x8*>(Rb + (size_t)(c0 + cl) * 64 + grp * 8);
  const bf16x8 Rf1 = *reinterpret_cast<const bf16x8*>(Rb + (size_t)(c0 + cl) * 64 + 32 + grp * 8);
  const int cb = c0 + grp * 4;
  const float4 rmu4 = *reinterpret_cast<const float4*>(rmuB + (size_t)(b0 + cl) * 512 + cb);
  const float4 y4   = *reinterpret_cast<const float4*>(yB + (size_t)(b0 + cl) * 512 + cb);
  const float sn0 = fmaf(2.f, y4.x, -1.f), sn1 = fmaf(2.f, y4.y, -1.f);
  const float sn2 = fmaf(2.f, y4.z, -1.f), sn3 = fmaf(2.f, y4.w, -1.f);
  const bool v0 = cb + 0 < Csz, v1 = cb + 1 < Csz, v2 = cb + 2 < Csz, v3 = cb + 3 < Csz;

  const bf16x8* nf = reinterpret_cast<const bf16x8*>(nfB);
  const int sbase = sg * 10;
  int base = (sbase * 32 + bt) * 128 + lane;     // stride per s: 4096

  bf16x8 fa0 = nf[base],        fa1 = nf[base + 64];
  bf16x8 fb0 = nf[base + 4096], fb1 = nf[base + 4096 + 64];

  #pragma unroll 1
  for (int i = 0; i < 10; i += 2) {
    bf16x8 na0, na1, nb0, nb1;
    if (i < 8) {
      na0 = nf[base + 8192];  na1 = nf[base + 8192 + 64];
      nb0 = nf[base + 12288]; nb1 = nf[base + 12288 + 64];
    }
    f32x4 accA = {0.f, 0.f, 0.f, 0.f};
    f32x4 accB = {0.f, 0.f, 0.f, 0.f};
    accA = __builtin_amdgcn_mfma_f32_16x16x32_bf16(Rf0, fa0, accA, 0, 0, 0);
    accB = __builtin_amdgcn_mfma_f32_16x16x32_bf16(Rf0, fb0, accB, 0, 0, 0);
    accA = __builtin_amdgcn_mfma_f32_16x16x32_bf16(Rf1, fa1, accA, 0, 0, 0);
    accB = __builtin_amdgcn_mfma_f32_16x16x32_bf16(Rf1, fb1, accB, 0, 0, 0);
    float lpA = 0.f, lpB = 0.f;
    lpA += v0 ? log_probit((accA[0] + rmu4.x) * sn0) : 0.f;
    lpB += v0 ? log_probit((accB[0] + rmu4.x) * sn0) : 0.f;
    lpA += v1 ? log_probit((accA[1] + rmu4.y) * sn1) : 0.f;
    lpB += v1 ? log_probit((accB[1] + rmu4.y) * sn1) : 0.f;
    lpA += v2 ? log_probit((accA[2] + rmu4.z) * sn2) : 0.f;
    lpB += v2 ? log_probit((accB[2] + rmu4.z) * sn2) : 0.f;
    lpA += v3 ? log_probit((accA[3] + rmu4.w) * sn3) : 0.f;
    lpB += v3 ? log_probit((accB[3] + rmu4.w) * sn3) : 0.f;
    lpA += __shfl_xor(lpA, 16, 64);
    lpA += __shfl_xor(lpA, 32, 64);
    lpB += __shfl_xor(lpB, 16, 64);
    lpB += __shfl_xor(lpB, 32, 64);
    if (lane < 16) {
      const int s = sbase + i;
      lp_part[(size_t)(s * 32 + ct) * 512 + b0 + lane] = lpA;
      lp_part[(size_t)((s + 1) * 32 + ct) * 512 + b0 + lane] = lpB;
    }
    base += 8192;
    fa0 = na0; fa1 = na1; fb0 = nb0; fb1 = nb1;
  }
}

// ---------------- TAIL: ctsum(200u) -> bar -> nll(8u) -> bar -> finals (200 blocks) ----------------
__global__ __launch_bounds__(256) void tail_kernel(
    const float* __restrict__ lp_part, float* __restrict__ lp_sum,
    float* __restrict__ nll_b, const float* __restrict__ ce_part,
    const float* __restrict__ l2_part, float* __restrict__ out4,
    unsigned* __restrict__ cnt) {
  __shared__ float tsm[520];
  const int bid = (int)blockIdx.x;
  const int tid = (int)threadIdx.x;

  // phase 1: ctsum (coalesced, 200 units of 256)
  {
    const int i = bid * 256 + tid;   // 51200
    const int s = i >> 9, b = i & 511;
    const float* p = lp_part + (size_t)s * 16384 + b;
    float a0 = 0.f, a1 = 0.f, a2 = 0.f, a3 = 0.f;
    #pragma unroll
    for (int ct = 0; ct < 32; ct += 4) {
      a0 += p[(ct + 0) * 512];
      a1 += p[(ct + 1) * 512];
      a2 += p[(ct + 2) * 512];
      a3 += p[(ct + 3) * 512];
    }
    lp_sum[i] = (a0 + a1) + (a2 + a3);
  }
  phase_arrive(cnt + 2);
  if (bid >= 8) return;               // non-participants done (their arrival is counted)
  phase_wait(cnt + 2, 200);

  // phase 2: per-b LSE over S (8 blocks x 64 b, 4-way s-parallel)
  {
    float* sm = tsm;                  // [4][64]
    float* sse = tsm + 256;           // [4][64]
    const int bl = tid & 63;
    const int sc = tid >> 6;
    const int b = bid * 64 + bl;
    float m = -3.0e38f, se = 0.f;
    for (int s = sc * 25; s < sc * 25 + 25; ++s) {
      const float v = lp_sum[(size_t)s * Bsz + b];
      const float mn = fmaxf(m, v);
      se = se * __expf(m - mn) + __expf(v - mn);
      m = mn;
    }
    sm[sc * 64 + bl] = m; sse[sc * 64 + bl] = se;
    __syncthreads();
    if (sc == 0) {
      float M = sm[bl];
      #pragma unroll
      for (int i = 1; i < 4; ++i) M = fmaxf(M, sm[i * 64 + bl]);
      float SE = 0.f;
      #pragma unroll
      for (int i = 0; i < 4; ++i) SE += sse[i * 64 + bl] * __expf(sm[i * 64 + bl] - M);
      nll_b[b] = -__logf(SE * (1.f / (float)Ssz)) - M;
    }
  }
  phase_arrive(cnt + 3);
  if (bid != 0) return;
  phase_wait(cnt + 3, 8);

  // phase 3: finals (block 0)
  {
    float* red = tsm + 512;
    const float snll = block_reduce_sum(nll_b[tid] + nll_b[tid + 256], red);
    float ce = 0.f;
    #pragma unroll
    for (int i = 0; i < 32; ++i) ce += ce_part[i * 256 + tid];
    const float sce = block_reduce_sum(ce, red);
    const float sl2 = block_reduce_sum((tid < 64) ? l2_part[tid] : 0.f, red);
    if (tid == 0) {
      const float nll = snll / (float)Bsz;
      const float marg = -sce / (float)Bsz;
      const float l2v = WDf * sl2;
      out4[0] = nll;
      out4[1] = marg;
      out4[2] = l2v;
      out4[3] = l2v + nll;
    }
  }
}

// ---------------- launch ----------------
extern "C" void kernel_launch(void* const* d_in, const int* in_sizes, int n_in,
                              void* d_out, int out_size, void* d_ws, size_t ws_size,
                              hipStream_t stream) {
  const float* X = (const float*)d_in[0];
  const float* Y = (const float*)d_in[1];
  const float* noise = (const float*)d_in[2];
  const float* W1 = (const float*)d_in[3];
  const float* b1 = (const float*)d_in[4];
  const float* W2 = (const float*)d_in[5];
  const float* b2 = (const float*)d_in[6];
  const float* W3 = (const float*)d_in[7];
  const float* b3 = (const float*)d_in[8];
  const float* Wmu = (const float*)d_in[9];
  const float* bmu = (const float*)d_in[10];
  const float* rss = (const float*)d_in[11];

  float* ws = (float*)d_ws;
  // lp_part aliases trunk temporaries (h*, feat dead before logprob writes)
  float* lp_part = ws;                    // 32*100*512 = 1638400
  float* h1 = ws;                         // 512*128
  float* h2 = h1 + 65536;                 // 512*256
  float* feat = h2 + 131072;              // 512*256   (ends 327680 < 1638400)
  float* B0 = ws + 1638400;
  float* sqrtcov = B0;                    // 512
  float* rmuB = sqrtcov + 512;            // 512*512
  float* yB = rmuB + 262144;              // 512*512
  float* ce_part = yB + 262144;           // 16*512
  float* nll_b = ce_part + 8192;          // 512
  float* l2_part = nll_b + 512;           // 128
  float* lp_sum = l2_part + 128;          // 100*512 = 51200
  short* Rb = (short*)(lp_sum + 51200);   // 512*64 shorts
  short* nfB = Rb + 32768;                // 100*32*128*8 = 3276800 shorts
  unsigned* cnt = (unsigned*)(nfB + 3276800);   // 8 phase counters

  float* out_prob = (float*)d_out;
  float* out4 = out_prob + (size_t)Bsz * Csz;

  prep_kernel<<<dim3(936), 256, 0, stream>>>(noise, nfB, rss, Rb, sqrtcov,
                                             X, W1, b1, h1, W2, W3, Wmu, l2_part, cnt);

  trunk_kernel<<<dim3(256), 256, 0, stream>>>(h1, W2, b2, h2, W3, b3, feat, Wmu, bmu,
                                              Y, sqrtcov, out_prob, rmuB, yB, ce_part, cnt);

  logprob_s<<<dim3(2560), 256, 0, stream>>>(nfB, Rb, rmuB, yB, lp_part);

  tail_kernel<<<dim3(200), 256, 0, stream>>>(lp_part, lp_sum, nll_b, ce_part,
                                             l2_part, out4, cnt);
}

// Round 12
// 87.509 us; speedup vs baseline: 1.9637x; 1.9637x over previous
//
#include <hip/hip_runtime.h>
#include <cstddef>

#define EPS1f 1e-6f
#define WDf   1e-5f

constexpr int Bsz = 512, Csz = 500, Zsz = 64, Ssz = 100;

typedef short bf16x8 __attribute__((ext_vector_type(8)));
typedef float f32x4 __attribute__((ext_vector_type(4)));

__device__ inline short f2bf(float f) {
  union { float f; unsigned u; } v; v.f = f;
  unsigned r = (v.u + 0x7fffu + ((v.u >> 16) & 1u)) >> 16;   // RNE
  return (short)r;
}

// log( Phi(t)*(1-eps) + eps/2 )  via A&S 7.1.26 erfc approx (|err|<=1.5e-7)
__device__ inline float log_probit(float t) {
  const float u = t * -0.70710678118654752f;
  const float au = fabsf(u);
  const float s = 1.f / fmaf(0.3275911f, au, 1.f);
  float p = fmaf(1.061405429f, s, -1.453152027f);
  p = fmaf(p, s, 1.421413741f);
  p = fmaf(p, s, -0.284496736f);
  p = fmaf(p, s, 0.254829592f);
  p = p * s;
  const float e = __expf(-au * au);
  const float f = p * e;
  const float erfc_u = (u < 0.f) ? (2.f - f) : f;
  const float E = fmaf(0.5f * erfc_u, 1.f - EPS1f, 0.5f * EPS1f);
  return __logf(E);
}

__device__ inline float block_reduce_sum(float v, float* red) {
  #pragma unroll
  for (int off = 32; off > 0; off >>= 1) v += __shfl_down(v, off, 64);
  const int lane = threadIdx.x & 63, wid = threadIdx.x >> 6;
  if (lane == 0) red[wid] = v;
  __syncthreads();
  float r = 0.f;
  if (threadIdx.x == 0) {
    const int nw = blockDim.x >> 6;
    for (int i = 0; i < nw; ++i) r += red[i];
  }
  __syncthreads();
  return r;   // valid in thread 0 only
}

// ---------------- 32x32 double-buffered GEMM body ----------------
__device__ __forceinline__ void gemm32_body(
    const float* __restrict__ A, const float* __restrict__ W,
    const float* __restrict__ bias, float* __restrict__ out,
    int M, int N, int K, int bn0, int bm0, float* As_, float* Ws_, bool relu) {
  const int tid = threadIdx.x;
  const int bn = bn0 * 32, bm = bm0 * 32;
  const int sm = tid >> 3, sk4 = (tid & 7) * 4;
  const int sk = tid >> 3, sn4 = (tid & 7) * 4;
  const int tn = tid & 15, tm = tid >> 4;
  #define AS_(b, k, m) As_[(b) * 1152 + (k) * 36 + (m)]
  #define WS_(b, k, n) Ws_[(b) * 1152 + (k) * 36 + (n)]
  auto loadW = [&](int kt, float4& wv) {
    const float* wrow = W + (size_t)(kt + sk) * N;
    const int nn = bn + sn4;
    if (nn + 3 < N) wv = *reinterpret_cast<const float4*>(wrow + nn);
    else {
      wv.x = (nn + 0 < N) ? wrow[nn + 0] : 0.f;
      wv.y = (nn + 1 < N) ? wrow[nn + 1] : 0.f;
      wv.z = (nn + 2 < N) ? wrow[nn + 2] : 0.f;
      wv.w = (nn + 3 < N) ? wrow[nn + 3] : 0.f;
    }
  };
  {
    float4 av = *reinterpret_cast<const float4*>(A + (size_t)(bm + sm) * K + sk4);
    float4 wv; loadW(0, wv);
    AS_(0, sk4 + 0, sm) = av.x; AS_(0, sk4 + 1, sm) = av.y;
    AS_(0, sk4 + 2, sm) = av.z; AS_(0, sk4 + 3, sm) = av.w;
    *reinterpret_cast<float4*>(&WS_(0, sk, sn4)) = wv;
  }
  __syncthreads();
  float acc[2][2] = {};
  int pb = 0;
  for (int kt = 0; kt < K; kt += 32) {
    const bool more = (kt + 32) < K;
    float4 av2, wv2;
    if (more) {
      av2 = *reinterpret_cast<const float4*>(A + (size_t)(bm + sm) * K + kt + 32 + sk4);
      loadW(kt + 32, wv2);
    }
    #pragma unroll
    for (int k = 0; k < 32; ++k) {
      const float2 a = *reinterpret_cast<const float2*>(&AS_(pb, k, tm * 2));
      const float2 w = *reinterpret_cast<const float2*>(&WS_(pb, k, tn * 2));
      acc[0][0] = fmaf(a.x, w.x, acc[0][0]);
      acc[0][1] = fmaf(a.x, w.y, acc[0][1]);
      acc[1][0] = fmaf(a.y, w.x, acc[1][0]);
      acc[1][1] = fmaf(a.y, w.y, acc[1][1]);
    }
    if (more) {
      const int nb = pb ^ 1;
      AS_(nb, sk4 + 0, sm) = av2.x; AS_(nb, sk4 + 1, sm) = av2.y;
      AS_(nb, sk4 + 2, sm) = av2.z; AS_(nb, sk4 + 3, sm) = av2.w;
      *reinterpret_cast<float4*>(&WS_(nb, sk, sn4)) = wv2;
      __syncthreads();
      pb = nb;
    }
  }
  #pragma unroll
  for (int j = 0; j < 2; ++j) {
    const int n = bn + tn * 2 + j;
    if (n >= N) continue;
    const float bv = bias[n];
    #pragma unroll
    for (int i = 0; i < 2; ++i) {
      const int m = bm + tm * 2 + i;
      float v = acc[i][j] + bv;
      if (relu) v = fmaxf(v, 0.f);
      out[(size_t)m * N + n] = v;
    }
  }
  #undef AS_
  #undef WS_
}

// ---------------- PREP: nprep(0-799) | sqrtcov(800-807) | RbF(808-823) | l2(824-887) | gemm1(888-951) ----------------
__global__ __launch_bounds__(256) void prep_kernel(
    const float* __restrict__ noise, short* __restrict__ nfB,
    const float* __restrict__ R, short* __restrict__ RbF, float* __restrict__ sqrtcov,
    const float* __restrict__ X, const float* __restrict__ W1,
    const float* __restrict__ b1, float* __restrict__ h1,
    const float* __restrict__ W2, const float* __restrict__ W3,
    const float* __restrict__ Wmu, float* __restrict__ l2_part) {
  __shared__ float smem[2304 * 2];
  const int blk = blockIdx.x;
  const int tid = threadIdx.x;
  if (blk < 800) {
    // noise -> bf16 MFMA-fragment layout
    const int g = blk * 256 + tid;       // 204800
    const int s = g >> 11;
    const int r = g & 2047;
    const int bt = r >> 6;
    const int ln = r & 63;
    const int cl = ln & 15, grp = ln >> 4;
    const float* src = noise + ((size_t)(s * 512 + bt * 16 + cl) * 64 + grp * 8);
    const float4 a = *reinterpret_cast<const float4*>(src);
    const float4 b = *reinterpret_cast<const float4*>(src + 4);
    const float4 c = *reinterpret_cast<const float4*>(src + 32);
    const float4 d = *reinterpret_cast<const float4*>(src + 36);
    bf16x8* dst = reinterpret_cast<bf16x8*>(nfB);
    const int u = (s * 32 + bt) * 128 + ln;
    dst[u]      = bf16x8{ f2bf(a.x), f2bf(a.y), f2bf(a.z), f2bf(a.w),
                          f2bf(b.x), f2bf(b.y), f2bf(b.z), f2bf(b.w) };
    dst[u + 64] = bf16x8{ f2bf(c.x), f2bf(c.y), f2bf(c.z), f2bf(c.w),
                          f2bf(d.x), f2bf(d.y), f2bf(d.z), f2bf(d.w) };
  } else if (blk < 808) {
    // sqrt(cov_diag): 4 threads per c
    const int idx = (blk - 800) * 256 + tid;   // 0..2047
    const int c = idx >> 2;
    const int zq = (idx & 3) * 16;
    const bool cv = c < Csz;
    const float* src = R + (size_t)c * Zsz + zq;
    float ss = 0.f;
    if (cv) {
      #pragma unroll
      for (int q = 0; q < 4; ++q) {
        const float4 r4 = *reinterpret_cast<const float4*>(src + q * 4);
        ss = fmaf(r4.x, r4.x, ss); ss = fmaf(r4.y, r4.y, ss);
        ss = fmaf(r4.z, r4.z, ss); ss = fmaf(r4.w, r4.w, ss);
      }
    }
    ss += __shfl_xor(ss, 1, 64);
    ss += __shfl_xor(ss, 2, 64);
    if ((idx & 3) == 0 && cv) sqrtcov[c] = sqrtf(1.f + ss);
  } else if (blk < 824) {
    // R -> bf16 MFMA-fragment layout: entry e=(ct*2+f)*64+lane holds R[ct*16+cl][f*32+grp*8..+7]
    const int e = (blk - 808) * 256 + tid;     // 0..4095
    const int ct = e >> 7;
    const int f = (e >> 6) & 1;
    const int lane = e & 63;
    const int cl = lane & 15, grp = lane >> 4;
    const int c = ct * 16 + cl;
    bf16x8 out = {0, 0, 0, 0, 0, 0, 0, 0};
    if (c < Csz) {
      const float* src = R + (size_t)c * Zsz + f * 32 + grp * 8;
      const float4 a = *reinterpret_cast<const float4*>(src);
      const float4 b = *reinterpret_cast<const float4*>(src + 4);
      out = bf16x8{ f2bf(a.x), f2bf(a.y), f2bf(a.z), f2bf(a.w),
                    f2bf(b.x), f2bf(b.y), f2bf(b.z), f2bf(b.w) };
    }
    reinterpret_cast<bf16x8*>(RbF)[e] = out;
  } else if (blk < 888) {
    const int bid = blk - 824;
    const int gid = bid * 256 + tid;
    const int stride = 64 * 256;
    float s = 0.f;
    for (int i = gid; i < 65536; i += stride) { float v = W1[i]; s = fmaf(v, v, s); }
    for (int i = gid; i < 32768; i += stride) { float v = W2[i]; s = fmaf(v, v, s); }
    for (int i = gid; i < 65536; i += stride) { float v = W3[i]; s = fmaf(v, v, s); }
    for (int i = gid; i < 128000; i += stride) { float v = Wmu[i]; s = fmaf(v, v, s); }
    const float tot = block_reduce_sum(s, smem);
    if (tid == 0) l2_part[bid] = tot;
  } else {
    const int idx = blk - 888;                  // 0..63
    gemm32_body(X, W1, b1, h1, 512, 128, 512, idx & 3, idx >> 2,
                smem, smem + 2304, true);
  }
}

// ---------------- standalone 32x32 GEMM ----------------
template <bool RELU>
__global__ __launch_bounds__(256) void gemm32(
    const float* __restrict__ A, const float* __restrict__ W,
    const float* __restrict__ bias, float* __restrict__ out,
    int M, int N, int K) {
  __shared__ float smem[2304 * 2];
  gemm32_body(A, W, bias, out, M, N, K, blockIdx.x, blockIdx.y,
              smem, smem + 2304, RELU);
}

// ---------------- MU GEMM: -> indiv_prob, CE partials, fragment-ordered rmuP/snP ----------------
__global__ __launch_bounds__(256) void gemm32_mu(
    const float* __restrict__ A, const float* __restrict__ W,
    const float* __restrict__ bias, const float* __restrict__ Y,
    const float* __restrict__ sqrtcov,
    float* __restrict__ out_prob, float* __restrict__ rmuP, float* __restrict__ snP,
    float* __restrict__ ce_part, int M, int N, int K) {
  __shared__ float As[2][32][36];
  __shared__ float Ws[2][32][36];
  const int tid = threadIdx.x;
  const int bn = blockIdx.x * 32, bm = blockIdx.y * 32;
  const int sm = tid >> 3, sk4 = (tid & 7) * 4;
  const int sk = tid >> 3, sn4 = (tid & 7) * 4;
  const int tn = tid & 15, tm = tid >> 4;

  auto loadW = [&](int kt, float4& wv) {
    const float* wrow = W + (size_t)(kt + sk) * N;
    const int nn = bn + sn4;
    if (nn + 3 < N) wv = *reinterpret_cast<const float4*>(wrow + nn);
    else {
      wv.x = (nn + 0 < N) ? wrow[nn + 0] : 0.f;
      wv.y = (nn + 1 < N) ? wrow[nn + 1] : 0.f;
      wv.z = (nn + 2 < N) ? wrow[nn + 2] : 0.f;
      wv.w = (nn + 3 < N) ? wrow[nn + 3] : 0.f;
    }
  };
  {
    float4 av = *reinterpret_cast<const float4*>(A + (size_t)(bm + sm) * K + sk4);
    float4 wv; loadW(0, wv);
    As[0][sk4 + 0][sm] = av.x; As[0][sk4 + 1][sm] = av.y;
    As[0][sk4 + 2][sm] = av.z; As[0][sk4 + 3][sm] = av.w;
    *reinterpret_cast<float4*>(&Ws[0][sk][sn4]) = wv;
  }
  __syncthreads();
  float acc[2][2] = {};
  int pb = 0;
  for (int kt = 0; kt < K; kt += 32) {
    const bool more = (kt + 32) < K;
    float4 av2, wv2;
    if (more) {
      av2 = *reinterpret_cast<const float4*>(A + (size_t)(bm + sm) * K + kt + 32 + sk4);
      loadW(kt + 32, wv2);
    }
    #pragma unroll
    for (int k = 0; k < 32; ++k) {
      const float2 a = *reinterpret_cast<const float2*>(&As[pb][k][tm * 2]);
      const float2 w = *reinterpret_cast<const float2*>(&Ws[pb][k][tn * 2]);
      acc[0][0] = fmaf(a.x, w.x, acc[0][0]);
      acc[0][1] = fmaf(a.x, w.y, acc[0][1]);
      acc[1][0] = fmaf(a.y, w.x, acc[1][0]);
      acc[1][1] = fmaf(a.y, w.y, acc[1][1]);
    }
    if (more) {
      const int nb = pb ^ 1;
      As[nb][sk4 + 0][sm] = av2.x; As[nb][sk4 + 1][sm] = av2.y;
      As[nb][sk4 + 2][sm] = av2.z; As[nb][sk4 + 3][sm] = av2.w;
      *reinterpret_cast<float4*>(&Ws[nb][sk][sn4]) = wv2;
      __syncthreads();
      pb = nb;
    }
  }
  float ce2[2] = {0.f, 0.f};
  #pragma unroll
  for (int i = 0; i < 2; ++i) {
    const int m = bm + tm * 2 + i;
    #pragma unroll
    for (int j = 0; j < 2; ++j) {
      const int n = bn + tn * 2 + j;
      if (n < N) {
        const float v = acc[i][j] + bias[n];
        const float sp = 1.f / (1.f + __expf(-1.70169f * v));
        const float p = fmaf(sp, 1.f - EPS1f, 0.5f * EPS1f);
        const float q = fmaf(1.f - sp, 1.f - EPS1f, 0.5f * EPS1f);
        const float y = Y[(size_t)m * N + n];
        out_prob[(size_t)m * N + n] = p;
        ce2[i] += __logf((y > 0.5f) ? p : q);
        // fragment-ordered: idx = (ct*32+bt)*256 + lane*4 + j, lane = grp*16+cl
        const int idx = (((n >> 4) * 32 + (m >> 4)) << 8)
                      + ((((n >> 2) & 3) * 16 + (m & 15)) << 2) + (n & 3);
        rmuP[idx] = v * sqrtcov[n];
        snP[idx] = (y > 0.5f) ? 1.f : -1.f;
      }
    }
  }
  #pragma unroll
  for (int off = 1; off < 16; off <<= 1) {
    ce2[0] += __shfl_xor(ce2[0], off, 64);
    ce2[1] += __shfl_xor(ce2[1], off, 64);
  }
  if (tn == 0) {
    const int m0 = bm + tm * 2;
    ce_part[(size_t)blockIdx.x * Bsz + m0] = ce2[0];
    ce_part[(size_t)blockIdx.x * Bsz + m0 + 1] = ce2[1];
  }
}

// ---------------- HOT: c-inner MFMA + probit log-likelihood, in-register c-accumulation ----------------
// wave = (s, bt, ch): 16 b-rows x 256 c's, 16 c-tile iters. grid = 100*16 = 1600 blocks.
// All inner-loop loads fully coalesced (fragment-ordered operands). No shfl/stores in loop.
__global__ __launch_bounds__(256, 6) void logprob_s2(
    const short* __restrict__ nfB, const short* __restrict__ RbF,
    const float* __restrict__ rmuP, const float* __restrict__ snP,
    float* __restrict__ lp2) {
  const int blk = blockIdx.x;          // s*16 + btg
  const int btg = blk & 15;
  const int s = blk >> 4;
  const int wid = threadIdx.x >> 6;
  const int lane = threadIdx.x & 63;
  const int bt = btg * 2 + (wid & 1);
  const int ch = wid >> 1;
  const int grp = lane >> 4;

  const bf16x8* nf = reinterpret_cast<const bf16x8*>(nfB);
  const int nbase = (s * 32 + bt) * 128 + lane;
  const bf16x8 n0 = nf[nbase];               // resident: noise frag (8 VGPR)
  const bf16x8 n1 = nf[nbase + 64];
  const bf16x8* rf = reinterpret_cast<const bf16x8*>(RbF);

  float lpl = 0.f;
  #pragma unroll 2
  for (int t = 0; t < 16; ++t) {
    const int ct = ch * 16 + t;
    const bf16x8 Rf0 = rf[(ct * 2 + 0) * 64 + lane];
    const bf16x8 Rf1 = rf[(ct * 2 + 1) * 64 + lane];
    f32x4 acc = {0.f, 0.f, 0.f, 0.f};
    acc = __builtin_amdgcn_mfma_f32_16x16x32_bf16(Rf0, n0, acc, 0, 0, 0);
    acc = __builtin_amdgcn_mfma_f32_16x16x32_bf16(Rf1, n1, acc, 0, 0, 0);
    const int fb = (ct * 32 + bt) * 256 + lane * 4;
    const float4 rmu4 = *reinterpret_cast<const float4*>(rmuP + fb);
    const float4 sn4  = *reinterpret_cast<const float4*>(snP + fb);
    const int cb = ct * 16 + grp * 4;
    lpl += (cb + 0 < Csz) ? log_probit((acc[0] + rmu4.x) * sn4.x) : 0.f;
    lpl += (cb + 1 < Csz) ? log_probit((acc[1] + rmu4.y) * sn4.y) : 0.f;
    lpl += (cb + 2 < Csz) ? log_probit((acc[2] + rmu4.z) * sn4.z) : 0.f;
    lpl += (cb + 3 < Csz) ? log_probit((acc[3] + rmu4.w) * sn4.w) : 0.f;
  }
  lpl += __shfl_xor(lpl, 16, 64);
  lpl += __shfl_xor(lpl, 32, 64);
  if (lane < 16) lp2[(size_t)(ch * Ssz + s) * 512 + bt * 16 + lane] = lpl;
}

// ---------------- per-b log-sum-exp over S (4-way s-parallel, 2-chunk fused) ----------------
__global__ __launch_bounds__(256) void nll_kernel(const float* __restrict__ lp2,
                                                  float* __restrict__ nll_b) {
  __shared__ float sm[4][64], sse[4][64];
  const int bl = threadIdx.x & 63;
  const int sc = threadIdx.x >> 6;
  const int b = blockIdx.x * 64 + bl;
  float m = -3.0e38f, se = 0.f;
  for (int s = sc * 25; s < sc * 25 + 25; ++s) {
    const float v = lp2[(size_t)s * 512 + b] + lp2[(size_t)(Ssz + s) * 512 + b];
    const float mn = fmaxf(m, v);
    se = se * __expf(m - mn) + __expf(v - mn);
    m = mn;
  }
  sm[sc][bl] = m; sse[sc][bl] = se;
  __syncthreads();
  if (sc == 0) {
    float M = sm[0][bl];
    #pragma unroll
    for (int i = 1; i < 4; ++i) M = fmaxf(M, sm[i][bl]);
    float SE = 0.f;
    #pragma unroll
    for (int i = 0; i < 4; ++i) SE += sse[i][bl] * __expf(sm[i][bl] - M);
    nll_b[b] = -__logf(SE * (1.f / (float)Ssz)) - M;
  }
}

// ---------------- final scalars ----------------
__global__ __launch_bounds__(256) void finals_kernel(
    const float* __restrict__ nll_b, const float* __restrict__ ce_part,
    const float* __restrict__ l2_part, int nparts, float* __restrict__ out4) {
  __shared__ float red[4];
  const int t = threadIdx.x;
  const float snll = block_reduce_sum(nll_b[t] + nll_b[t + 256], red);
  float ce = 0.f;
  #pragma unroll
  for (int i = 0; i < 32; ++i) ce += ce_part[i * 256 + t];
  const float sce = block_reduce_sum(ce, red);
  const float sl2 = block_reduce_sum((t < nparts) ? l2_part[t] : 0.f, red);
  if (t == 0) {
    const float nll = snll / (float)Bsz;
    const float marg = -sce / (float)Bsz;
    const float l2v = WDf * sl2;
    out4[0] = nll;
    out4[1] = marg;
    out4[2] = l2v;
    out4[3] = l2v + nll;
  }
}

// ---------------- launch ----------------
extern "C" void kernel_launch(void* const* d_in, const int* in_sizes, int n_in,
                              void* d_out, int out_size, void* d_ws, size_t ws_size,
                              hipStream_t stream) {
  const float* X = (const float*)d_in[0];
  const float* Y = (const float*)d_in[1];
  const float* noise = (const float*)d_in[2];
  const float* W1 = (const float*)d_in[3];
  const float* b1 = (const float*)d_in[4];
  const float* W2 = (const float*)d_in[5];
  const float* b2 = (const float*)d_in[6];
  const float* W3 = (const float*)d_in[7];
  const float* b3 = (const float*)d_in[8];
  const float* Wmu = (const float*)d_in[9];
  const float* bmu = (const float*)d_in[10];
  const float* rss = (const float*)d_in[11];

  float* ws = (float*)d_ws;
  float* h1 = ws;                         // 512*128
  float* h2 = h1 + 65536;                 // 512*256
  float* feat = h2 + 131072;              // 512*256   (ends 327680)
  float* B0 = ws + 327680;
  float* sqrtcov = B0;                    // 512
  float* rmuP = sqrtcov + 512;            // 512*512 fragment-ordered
  float* snP = rmuP + 262144;             // 512*512 fragment-ordered
  float* ce_part = snP + 262144;          // 16*512
  float* nll_b = ce_part + 8192;          // 512
  float* l2_part = nll_b + 512;           // 128
  float* lp2 = l2_part + 128;             // 2*100*512 = 102400
  short* RbF = (short*)(lp2 + 102400);    // 4096 entries * 8 shorts = 32768 shorts
  short* nfB = RbF + 32768;               // 100*32*128*8 = 3276800 shorts

  float* out_prob = (float*)d_out;
  float* out4 = out_prob + (size_t)Bsz * Csz;

  prep_kernel<<<dim3(952), 256, 0, stream>>>(noise, nfB, rss, RbF, sqrtcov,
                                             X, W1, b1, h1, W2, W3, Wmu, l2_part);

  gemm32<true><<<dim3(8, 16), 256, 0, stream>>>(h1, W2, b2, h2, 512, 256, 128);
  gemm32<true><<<dim3(8, 16), 256, 0, stream>>>(h2, W3, b3, feat, 512, 256, 256);
  gemm32_mu<<<dim3(16, 16), 256, 0, stream>>>(feat, Wmu, bmu, Y, sqrtcov,
                                              out_prob, rmuP, snP, ce_part, 512, 500, 256);

  logprob_s2<<<dim3(1600), 256, 0, stream>>>(nfB, RbF, rmuP, snP, lp2);
  nll_kernel<<<dim3(8), 256, 0, stream>>>(lp2, nll_b);

  finals_kernel<<<dim3(1), 256, 0, stream>>>(nll_b, ce_part, l2_part, 64, out4);
}

// Round 13
// 83.981 us; speedup vs baseline: 2.0462x; 1.0420x over previous
//
#include <hip/hip_runtime.h>
#include <cstddef>

#define EPS1f 1e-6f
#define WDf   1e-5f

constexpr int Bsz = 512, Csz = 500, Zsz = 64, Ssz = 100;

typedef short bf16x8 __attribute__((ext_vector_type(8)));
typedef float f32x4 __attribute__((ext_vector_type(4)));

__device__ inline short f2bf(float f) {
  union { float f; unsigned u; } v; v.f = f;
  unsigned r = (v.u + 0x7fffu + ((v.u >> 16) & 1u)) >> 16;   // RNE
  return (short)r;
}

// log( Phi(t)*(1-eps) + eps/2 )  via A&S 7.1.26 erfc approx (|err|<=1.5e-7)
// v_rcp_f32 instead of IEEE divide: ~9 insts -> 1, rel err ~1e-7 (harmless here)
__device__ inline float log_probit(float t) {
  const float u = t * -0.70710678118654752f;
  const float au = fabsf(u);
  const float s = __builtin_amdgcn_rcpf(fmaf(0.3275911f, au, 1.f));
  float p = fmaf(1.061405429f, s, -1.453152027f);
  p = fmaf(p, s, 1.421413741f);
  p = fmaf(p, s, -0.284496736f);
  p = fmaf(p, s, 0.254829592f);
  p = p * s;
  const float e = __expf(-au * au);
  const float f = p * e;
  const float erfc_u = (u < 0.f) ? (2.f - f) : f;
  const float E = fmaf(0.5f * erfc_u, 1.f - EPS1f, 0.5f * EPS1f);
  return __logf(E);
}

__device__ inline float block_reduce_sum(float v, float* red) {
  #pragma unroll
  for (int off = 32; off > 0; off >>= 1) v += __shfl_down(v, off, 64);
  const int lane = threadIdx.x & 63, wid = threadIdx.x >> 6;
  if (lane == 0) red[wid] = v;
  __syncthreads();
  float r = 0.f;
  if (threadIdx.x == 0) {
    const int nw = blockDim.x >> 6;
    for (int i = 0; i < nw; ++i) r += red[i];
  }
  __syncthreads();
  return r;   // valid in thread 0 only
}

// ---------------- 32x32 double-buffered GEMM body ----------------
__device__ __forceinline__ void gemm32_body(
    const float* __restrict__ A, const float* __restrict__ W,
    const float* __restrict__ bias, float* __restrict__ out,
    int M, int N, int K, int bn0, int bm0, float* As_, float* Ws_, bool relu) {
  const int tid = threadIdx.x;
  const int bn = bn0 * 32, bm = bm0 * 32;
  const int sm = tid >> 3, sk4 = (tid & 7) * 4;
  const int sk = tid >> 3, sn4 = (tid & 7) * 4;
  const int tn = tid & 15, tm = tid >> 4;
  #define AS_(b, k, m) As_[(b) * 1152 + (k) * 36 + (m)]
  #define WS_(b, k, n) Ws_[(b) * 1152 + (k) * 36 + (n)]
  auto loadW = [&](int kt, float4& wv) {
    const float* wrow = W + (size_t)(kt + sk) * N;
    const int nn = bn + sn4;
    if (nn + 3 < N) wv = *reinterpret_cast<const float4*>(wrow + nn);
    else {
      wv.x = (nn + 0 < N) ? wrow[nn + 0] : 0.f;
      wv.y = (nn + 1 < N) ? wrow[nn + 1] : 0.f;
      wv.z = (nn + 2 < N) ? wrow[nn + 2] : 0.f;
      wv.w = (nn + 3 < N) ? wrow[nn + 3] : 0.f;
    }
  };
  {
    float4 av = *reinterpret_cast<const float4*>(A + (size_t)(bm + sm) * K + sk4);
    float4 wv; loadW(0, wv);
    AS_(0, sk4 + 0, sm) = av.x; AS_(0, sk4 + 1, sm) = av.y;
    AS_(0, sk4 + 2, sm) = av.z; AS_(0, sk4 + 3, sm) = av.w;
    *reinterpret_cast<float4*>(&WS_(0, sk, sn4)) = wv;
  }
  __syncthreads();
  float acc[2][2] = {};
  int pb = 0;
  for (int kt = 0; kt < K; kt += 32) {
    const bool more = (kt + 32) < K;
    float4 av2, wv2;
    if (more) {
      av2 = *reinterpret_cast<const float4*>(A + (size_t)(bm + sm) * K + kt + 32 + sk4);
      loadW(kt + 32, wv2);
    }
    #pragma unroll
    for (int k = 0; k < 32; ++k) {
      const float2 a = *reinterpret_cast<const float2*>(&AS_(pb, k, tm * 2));
      const float2 w = *reinterpret_cast<const float2*>(&WS_(pb, k, tn * 2));
      acc[0][0] = fmaf(a.x, w.x, acc[0][0]);
      acc[0][1] = fmaf(a.x, w.y, acc[0][1]);
      acc[1][0] = fmaf(a.y, w.x, acc[1][0]);
      acc[1][1] = fmaf(a.y, w.y, acc[1][1]);
    }
    if (more) {
      const int nb = pb ^ 1;
      AS_(nb, sk4 + 0, sm) = av2.x; AS_(nb, sk4 + 1, sm) = av2.y;
      AS_(nb, sk4 + 2, sm) = av2.z; AS_(nb, sk4 + 3, sm) = av2.w;
      *reinterpret_cast<float4*>(&WS_(nb, sk, sn4)) = wv2;
      __syncthreads();
      pb = nb;
    }
  }
  #pragma unroll
  for (int j = 0; j < 2; ++j) {
    const int n = bn + tn * 2 + j;
    if (n >= N) continue;
    const float bv = bias[n];
    #pragma unroll
    for (int i = 0; i < 2; ++i) {
      const int m = bm + tm * 2 + i;
      float v = acc[i][j] + bv;
      if (relu) v = fmaxf(v, 0.f);
      out[(size_t)m * N + n] = v;
    }
  }
  #undef AS_
  #undef WS_
}

// ---------------- PREP: nprep(0-799) | sqrtcov(800-807) | RbF(808-823) | l2(824-887)
// | gemm1(888-951) | padinit(952-983) ----------------
__global__ __launch_bounds__(256) void prep_kernel(
    const float* __restrict__ noise, short* __restrict__ nfB,
    const float* __restrict__ R, short* __restrict__ RbF, float* __restrict__ sqrtcov,
    const float* __restrict__ X, const float* __restrict__ W1,
    const float* __restrict__ b1, float* __restrict__ h1,
    const float* __restrict__ W2, const float* __restrict__ W3,
    const float* __restrict__ Wmu, float* __restrict__ l2_part,
    float* __restrict__ rmuP, float* __restrict__ snP) {
  __shared__ float smem[2304 * 2];
  const int blk = blockIdx.x;
  const int tid = threadIdx.x;
  if (blk < 800) {
    // noise -> bf16 MFMA-fragment layout
    const int g = blk * 256 + tid;       // 204800
    const int s = g >> 11;
    const int r = g & 2047;
    const int bt = r >> 6;
    const int ln = r & 63;
    const int cl = ln & 15, grp = ln >> 4;
    const float* src = noise + ((size_t)(s * 512 + bt * 16 + cl) * 64 + grp * 8);
    const float4 a = *reinterpret_cast<const float4*>(src);
    const float4 b = *reinterpret_cast<const float4*>(src + 4);
    const float4 c = *reinterpret_cast<const float4*>(src + 32);
    const float4 d = *reinterpret_cast<const float4*>(src + 36);
    bf16x8* dst = reinterpret_cast<bf16x8*>(nfB);
    const int u = (s * 32 + bt) * 128 + ln;
    dst[u]      = bf16x8{ f2bf(a.x), f2bf(a.y), f2bf(a.z), f2bf(a.w),
                          f2bf(b.x), f2bf(b.y), f2bf(b.z), f2bf(b.w) };
    dst[u + 64] = bf16x8{ f2bf(c.x), f2bf(c.y), f2bf(c.z), f2bf(c.w),
                          f2bf(d.x), f2bf(d.y), f2bf(d.z), f2bf(d.w) };
  } else if (blk < 808) {
    // sqrt(cov_diag): 4 threads per c
    const int idx = (blk - 800) * 256 + tid;   // 0..2047
    const int c = idx >> 2;
    const int zq = (idx & 3) * 16;
    const bool cv = c < Csz;
    const float* src = R + (size_t)c * Zsz + zq;
    float ss = 0.f;
    if (cv) {
      #pragma unroll
      for (int q = 0; q < 4; ++q) {
        const float4 r4 = *reinterpret_cast<const float4*>(src + q * 4);
        ss = fmaf(r4.x, r4.x, ss); ss = fmaf(r4.y, r4.y, ss);
        ss = fmaf(r4.z, r4.z, ss); ss = fmaf(r4.w, r4.w, ss);
      }
    }
    ss += __shfl_xor(ss, 1, 64);
    ss += __shfl_xor(ss, 2, 64);
    if ((idx & 3) == 0 && cv) sqrtcov[c] = sqrtf(1.f + ss);
  } else if (blk < 824) {
    // R -> bf16 MFMA-fragment layout (zero-padded rows >= Csz)
    const int e = (blk - 808) * 256 + tid;     // 0..4095
    const int ct = e >> 7;
    const int f = (e >> 6) & 1;
    const int lane = e & 63;
    const int cl = lane & 15, grp = lane >> 4;
    const int c = ct * 16 + cl;
    bf16x8 out = {0, 0, 0, 0, 0, 0, 0, 0};
    if (c < Csz) {
      const float* src = R + (size_t)c * Zsz + f * 32 + grp * 8;
      const float4 a = *reinterpret_cast<const float4*>(src);
      const float4 b = *reinterpret_cast<const float4*>(src + 4);
      out = bf16x8{ f2bf(a.x), f2bf(a.y), f2bf(a.z), f2bf(a.w),
                    f2bf(b.x), f2bf(b.y), f2bf(b.z), f2bf(b.w) };
    }
    reinterpret_cast<bf16x8*>(RbF)[e] = out;
  } else if (blk < 888) {
    const int bid = blk - 824;
    const int gid = bid * 256 + tid;
    const int stride = 64 * 256;
    float s = 0.f;
    for (int i = gid; i < 65536; i += stride) { float v = W1[i]; s = fmaf(v, v, s); }
    for (int i = gid; i < 32768; i += stride) { float v = W2[i]; s = fmaf(v, v, s); }
    for (int i = gid; i < 65536; i += stride) { float v = W3[i]; s = fmaf(v, v, s); }
    for (int i = gid; i < 128000; i += stride) { float v = Wmu[i]; s = fmaf(v, v, s); }
    const float tot = block_reduce_sum(s, smem);
    if (tid == 0) l2_part[bid] = tot;
  } else if (blk < 952) {
    const int idx = blk - 888;                  // 0..63
    gemm32_body(X, W1, b1, h1, 512, 128, 512, idx & 3, idx >> 2,
                smem, smem + 2304, true);
  } else {
    // pad-init rmuP/snP for n in [496,512) (real 496-499 overwritten by gemm_mu later)
    const int g = (blk - 952) * 256 + tid;      // 0..8191
    const int m = g >> 4;
    const int n = 496 + (g & 15);
    const int idx = ((n >> 4) * 32 + (m >> 4)) * 256
                  + (((n >> 2) & 3) * 16 + (m & 15)) * 4 + (n & 3);
    rmuP[idx] = 0.f;
    snP[idx] = 1.f;
  }
}

// ---------------- standalone 32x32 GEMM ----------------
template <bool RELU>
__global__ __launch_bounds__(256) void gemm32(
    const float* __restrict__ A, const float* __restrict__ W,
    const float* __restrict__ bias, float* __restrict__ out,
    int M, int N, int K) {
  __shared__ float smem[2304 * 2];
  gemm32_body(A, W, bias, out, M, N, K, blockIdx.x, blockIdx.y,
              smem, smem + 2304, RELU);
}

// ---------------- MU GEMM: -> indiv_prob, CE partials, fragment-ordered rmuP/snP ----------------
__global__ __launch_bounds__(256) void gemm32_mu(
    const float* __restrict__ A, const float* __restrict__ W,
    const float* __restrict__ bias, const float* __restrict__ Y,
    const float* __restrict__ sqrtcov,
    float* __restrict__ out_prob, float* __restrict__ rmuP, float* __restrict__ snP,
    float* __restrict__ ce_part, int M, int N, int K) {
  __shared__ float As[2][32][36];
  __shared__ float Ws[2][32][36];
  const int tid = threadIdx.x;
  const int bn = blockIdx.x * 32, bm = blockIdx.y * 32;
  const int sm = tid >> 3, sk4 = (tid & 7) * 4;
  const int sk = tid >> 3, sn4 = (tid & 7) * 4;
  const int tn = tid & 15, tm = tid >> 4;

  auto loadW = [&](int kt, float4& wv) {
    const float* wrow = W + (size_t)(kt + sk) * N;
    const int nn = bn + sn4;
    if (nn + 3 < N) wv = *reinterpret_cast<const float4*>(wrow + nn);
    else {
      wv.x = (nn + 0 < N) ? wrow[nn + 0] : 0.f;
      wv.y = (nn + 1 < N) ? wrow[nn + 1] : 0.f;
      wv.z = (nn + 2 < N) ? wrow[nn + 2] : 0.f;
      wv.w = (nn + 3 < N) ? wrow[nn + 3] : 0.f;
    }
  };
  {
    float4 av = *reinterpret_cast<const float4*>(A + (size_t)(bm + sm) * K + sk4);
    float4 wv; loadW(0, wv);
    As[0][sk4 + 0][sm] = av.x; As[0][sk4 + 1][sm] = av.y;
    As[0][sk4 + 2][sm] = av.z; As[0][sk4 + 3][sm] = av.w;
    *reinterpret_cast<float4*>(&Ws[0][sk][sn4]) = wv;
  }
  __syncthreads();
  float acc[2][2] = {};
  int pb = 0;
  for (int kt = 0; kt < K; kt += 32) {
    const bool more = (kt + 32) < K;
    float4 av2, wv2;
    if (more) {
      av2 = *reinterpret_cast<const float4*>(A + (size_t)(bm + sm) * K + kt + 32 + sk4);
      loadW(kt + 32, wv2);
    }
    #pragma unroll
    for (int k = 0; k < 32; ++k) {
      const float2 a = *reinterpret_cast<const float2*>(&As[pb][k][tm * 2]);
      const float2 w = *reinterpret_cast<const float2*>(&Ws[pb][k][tn * 2]);
      acc[0][0] = fmaf(a.x, w.x, acc[0][0]);
      acc[0][1] = fmaf(a.x, w.y, acc[0][1]);
      acc[1][0] = fmaf(a.y, w.x, acc[1][0]);
      acc[1][1] = fmaf(a.y, w.y, acc[1][1]);
    }
    if (more) {
      const int nb = pb ^ 1;
      As[nb][sk4 + 0][sm] = av2.x; As[nb][sk4 + 1][sm] = av2.y;
      As[nb][sk4 + 2][sm] = av2.z; As[nb][sk4 + 3][sm] = av2.w;
      *reinterpret_cast<float4*>(&Ws[nb][sk][sn4]) = wv2;
      __syncthreads();
      pb = nb;
    }
  }
  float ce2[2] = {0.f, 0.f};
  #pragma unroll
  for (int i = 0; i < 2; ++i) {
    const int m = bm + tm * 2 + i;
    #pragma unroll
    for (int j = 0; j < 2; ++j) {
      const int n = bn + tn * 2 + j;
      if (n < N) {
        const float v = acc[i][j] + bias[n];
        const float sp = __builtin_amdgcn_rcpf(1.f + __expf(-1.70169f * v));
        const float p = fmaf(sp, 1.f - EPS1f, 0.5f * EPS1f);
        const float q = fmaf(1.f - sp, 1.f - EPS1f, 0.5f * EPS1f);
        const float y = Y[(size_t)m * N + n];
        out_prob[(size_t)m * N + n] = p;
        ce2[i] += __logf((y > 0.5f) ? p : q);
        // fragment-ordered: idx = (ct*32+bt)*256 + lane*4 + j
        const int idx = (((n >> 4) * 32 + (m >> 4)) << 8)
                      + ((((n >> 2) & 3) * 16 + (m & 15)) << 2) + (n & 3);
        rmuP[idx] = v * sqrtcov[n];
        snP[idx] = (y > 0.5f) ? 1.f : -1.f;
      }
    }
  }
  #pragma unroll
  for (int off = 1; off < 16; off <<= 1) {
    ce2[0] += __shfl_xor(ce2[0], off, 64);
    ce2[1] += __shfl_xor(ce2[1], off, 64);
  }
  if (tn == 0) {
    const int m0 = bm + tm * 2;
    ce_part[(size_t)blockIdx.x * Bsz + m0] = ce2[0];
    ce_part[(size_t)blockIdx.x * Bsz + m0 + 1] = ce2[1];
  }
}

// ---------------- HOT: c-inner MFMA + probit log-likelihood, mask-free ----------------
// wave = (s, bt, ch): 16 b-rows x 256 c's, 16 c-tile iters. grid = 1600.
// Padded c's (500-511, in ch=1) contribute exactly log(0.5) each -> constant, removed at write.
__global__ __launch_bounds__(256, 6) void logprob_s2(
    const short* __restrict__ nfB, const short* __restrict__ RbF,
    const float* __restrict__ rmuP, const float* __restrict__ snP,
    float* __restrict__ lp2) {
  const int blk = blockIdx.x;          // s*16 + btg
  const int btg = blk & 15;
  const int s = blk >> 4;
  const int wid = threadIdx.x >> 6;
  const int lane = threadIdx.x & 63;
  const int bt = btg * 2 + (wid & 1);
  const int ch = wid >> 1;

  const bf16x8* nf = reinterpret_cast<const bf16x8*>(nfB);
  const int nbase = (s * 32 + bt) * 128 + lane;
  const bf16x8 n0 = nf[nbase];               // resident noise frag
  const bf16x8 n1 = nf[nbase + 64];
  const bf16x8* rf = reinterpret_cast<const bf16x8*>(RbF);

  float lpl = 0.f;
  #pragma unroll 2
  for (int t = 0; t < 16; ++t) {
    const int ct = ch * 16 + t;
    const bf16x8 Rf0 = rf[(ct * 2 + 0) * 64 + lane];
    const bf16x8 Rf1 = rf[(ct * 2 + 1) * 64 + lane];
    f32x4 acc = {0.f, 0.f, 0.f, 0.f};
    acc = __builtin_amdgcn_mfma_f32_16x16x32_bf16(Rf0, n0, acc, 0, 0, 0);
    acc = __builtin_amdgcn_mfma_f32_16x16x32_bf16(Rf1, n1, acc, 0, 0, 0);
    const int fb = (ct * 32 + bt) * 256 + lane * 4;
    const float4 rmu4 = *reinterpret_cast<const float4*>(rmuP + fb);
    const float4 sn4  = *reinterpret_cast<const float4*>(snP + fb);
    lpl += log_probit((acc[0] + rmu4.x) * sn4.x);
    lpl += log_probit((acc[1] + rmu4.y) * sn4.y);
    lpl += log_probit((acc[2] + rmu4.z) * sn4.z);
    lpl += log_probit((acc[3] + rmu4.w) * sn4.w);
  }
  lpl += __shfl_xor(lpl, 16, 64);
  lpl += __shfl_xor(lpl, 32, 64);
  if (lane < 16) {
    // remove the 12 pad contributions (each = log(0.5)) from chunk 1
    const float fix = (ch == 1) ? 8.317766166719343f : 0.f;   // -12*log(0.5)
    lp2[(size_t)(ch * Ssz + s) * 512 + bt * 16 + lane] = lpl + fix;
  }
}

// ---------------- per-b log-sum-exp over S (4-way s-parallel, 2-chunk fused) ----------------
__global__ __launch_bounds__(256) void nll_kernel(const float* __restrict__ lp2,
                                                  float* __restrict__ nll_b) {
  __shared__ float sm[4][64], sse[4][64];
  const int bl = threadIdx.x & 63;
  const int sc = threadIdx.x >> 6;
  const int b = blockIdx.x * 64 + bl;
  float m = -3.0e38f, se = 0.f;
  for (int s = sc * 25; s < sc * 25 + 25; ++s) {
    const float v = lp2[(size_t)s * 512 + b] + lp2[(size_t)(Ssz + s) * 512 + b];
    const float mn = fmaxf(m, v);
    se = se * __expf(m - mn) + __expf(v - mn);
    m = mn;
  }
  sm[sc][bl] = m; sse[sc][bl] = se;
  __syncthreads();
  if (sc == 0) {
    float M = sm[0][bl];
    #pragma unroll
    for (int i = 1; i < 4; ++i) M = fmaxf(M, sm[i][bl]);
    float SE = 0.f;
    #pragma unroll
    for (int i = 0; i < 4; ++i) SE += sse[i][bl] * __expf(sm[i][bl] - M);
    nll_b[b] = -__logf(SE * (1.f / (float)Ssz)) - M;
  }
}

// ---------------- final scalars ----------------
__global__ __launch_bounds__(256) void finals_kernel(
    const float* __restrict__ nll_b, const float* __restrict__ ce_part,
    const float* __restrict__ l2_part, int nparts, float* __restrict__ out4) {
  __shared__ float red[4];
  const int t = threadIdx.x;
  const float snll = block_reduce_sum(nll_b[t] + nll_b[t + 256], red);
  float ce = 0.f;
  #pragma unroll
  for (int i = 0; i < 32; ++i) ce += ce_part[i * 256 + t];
  const float sce = block_reduce_sum(ce, red);
  const float sl2 = block_reduce_sum((t < nparts) ? l2_part[t] : 0.f, red);
  if (t == 0) {
    const float nll = snll / (float)Bsz;
    const float marg = -sce / (float)Bsz;
    const float l2v = WDf * sl2;
    out4[0] = nll;
    out4[1] = marg;
    out4[2] = l2v;
    out4[3] = l2v + nll;
  }
}

// ---------------- launch ----------------
extern "C" void kernel_launch(void* const* d_in, const int* in_sizes, int n_in,
                              void* d_out, int out_size, void* d_ws, size_t ws_size,
                              hipStream_t stream) {
  const float* X = (const float*)d_in[0];
  const float* Y = (const float*)d_in[1];
  const float* noise = (const float*)d_in[2];
  const float* W1 = (const float*)d_in[3];
  const float* b1 = (const float*)d_in[4];
  const float* W2 = (const float*)d_in[5];
  const float* b2 = (const float*)d_in[6];
  const float* W3 = (const float*)d_in[7];
  const float* b3 = (const float*)d_in[8];
  const float* Wmu = (const float*)d_in[9];
  const float* bmu = (const float*)d_in[10];
  const float* rss = (const float*)d_in[11];

  float* ws = (float*)d_ws;
  float* h1 = ws;                         // 512*128
  float* h2 = h1 + 65536;                 // 512*256
  float* feat = h2 + 131072;              // 512*256   (ends 327680)
  float* B0 = ws + 327680;
  float* sqrtcov = B0;                    // 512
  float* rmuP = sqrtcov + 512;            // 512*512 fragment-ordered
  float* snP = rmuP + 262144;             // 512*512 fragment-ordered
  float* ce_part = snP + 262144;          // 16*512
  float* nll_b = ce_part + 8192;          // 512
  float* l2_part = nll_b + 512;           // 128
  float* lp2 = l2_part + 128;             // 2*100*512 = 102400
  short* RbF = (short*)(lp2 + 102400);    // 4096 entries * 8 shorts
  short* nfB = RbF + 32768;               // 100*32*128*8 shorts

  float* out_prob = (float*)d_out;
  float* out4 = out_prob + (size_t)Bsz * Csz;

  prep_kernel<<<dim3(984), 256, 0, stream>>>(noise, nfB, rss, RbF, sqrtcov,
                                             X, W1, b1, h1, W2, W3, Wmu, l2_part,
                                             rmuP, snP);

  gemm32<true><<<dim3(8, 16), 256, 0, stream>>>(h1, W2, b2, h2, 512, 256, 128);
  gemm32<true><<<dim3(8, 16), 256, 0, stream>>>(h2, W3, b3, feat, 512, 256, 256);
  gemm32_mu<<<dim3(16, 16), 256, 0, stream>>>(feat, Wmu, bmu, Y, sqrtcov,
                                              out_prob, rmuP, snP, ce_part, 512, 500, 256);

  logprob_s2<<<dim3(1600), 256, 0, stream>>>(nfB, RbF, rmuP, snP, lp2);
  nll_kernel<<<dim3(8), 256, 0, stream>>>(lp2, nll_b);

  finals_kernel<<<dim3(1), 256, 0, stream>>>(nll_b, ce_part, l2_part, 64, out4);
}

// Round 14
// 73.693 us; speedup vs baseline: 2.3319x; 1.1396x over previous
//
#include <hip/hip_runtime.h>
#include <cstddef>

#define EPS1f 1e-6f
#define WDf   1e-5f

constexpr int Bsz = 512, Csz = 500, Zsz = 64, Ssz = 100;

typedef short bf16x8 __attribute__((ext_vector_type(8)));
typedef float f32x4 __attribute__((ext_vector_type(4)));

__device__ inline short f2bf(float f) {
  union { float f; unsigned u; } v; v.f = f;
  unsigned r = (v.u + 0x7fffu + ((v.u >> 16) & 1u)) >> 16;   // RNE
  return (short)r;
}

__device__ inline float block_reduce_sum(float v, float* red) {
  #pragma unroll
  for (int off = 32; off > 0; off >>= 1) v += __shfl_down(v, off, 64);
  const int lane = threadIdx.x & 63, wid = threadIdx.x >> 6;
  if (lane == 0) red[wid] = v;
  __syncthreads();
  float r = 0.f;
  if (threadIdx.x == 0) {
    const int nw = blockDim.x >> 6;
    for (int i = 0; i < nw; ++i) r += red[i];
  }
  __syncthreads();
  return r;   // valid in thread 0 only
}

// ---------------- 32x32 double-buffered GEMM body ----------------
__device__ __forceinline__ void gemm32_body(
    const float* __restrict__ A, const float* __restrict__ W,
    const float* __restrict__ bias, float* __restrict__ out,
    int M, int N, int K, int bn0, int bm0, float* As_, float* Ws_, bool relu) {
  const int tid = threadIdx.x;
  const int bn = bn0 * 32, bm = bm0 * 32;
  const int sm = tid >> 3, sk4 = (tid & 7) * 4;
  const int sk = tid >> 3, sn4 = (tid & 7) * 4;
  const int tn = tid & 15, tm = tid >> 4;
  #define AS_(b, k, m) As_[(b) * 1152 + (k) * 36 + (m)]
  #define WS_(b, k, n) Ws_[(b) * 1152 + (k) * 36 + (n)]
  auto loadW = [&](int kt, float4& wv) {
    const float* wrow = W + (size_t)(kt + sk) * N;
    const int nn = bn + sn4;
    if (nn + 3 < N) wv = *reinterpret_cast<const float4*>(wrow + nn);
    else {
      wv.x = (nn + 0 < N) ? wrow[nn + 0] : 0.f;
      wv.y = (nn + 1 < N) ? wrow[nn + 1] : 0.f;
      wv.z = (nn + 2 < N) ? wrow[nn + 2] : 0.f;
      wv.w = (nn + 3 < N) ? wrow[nn + 3] : 0.f;
    }
  };
  {
    float4 av = *reinterpret_cast<const float4*>(A + (size_t)(bm + sm) * K + sk4);
    float4 wv; loadW(0, wv);
    AS_(0, sk4 + 0, sm) = av.x; AS_(0, sk4 + 1, sm) = av.y;
    AS_(0, sk4 + 2, sm) = av.z; AS_(0, sk4 + 3, sm) = av.w;
    *reinterpret_cast<float4*>(&WS_(0, sk, sn4)) = wv;
  }
  __syncthreads();
  float acc[2][2] = {};
  int pb = 0;
  for (int kt = 0; kt < K; kt += 32) {
    const bool more = (kt + 32) < K;
    float4 av2, wv2;
    if (more) {
      av2 = *reinterpret_cast<const float4*>(A + (size_t)(bm + sm) * K + kt + 32 + sk4);
      loadW(kt + 32, wv2);
    }
    #pragma unroll
    for (int k = 0; k < 32; ++k) {
      const float2 a = *reinterpret_cast<const float2*>(&AS_(pb, k, tm * 2));
      const float2 w = *reinterpret_cast<const float2*>(&WS_(pb, k, tn * 2));
      acc[0][0] = fmaf(a.x, w.x, acc[0][0]);
      acc[0][1] = fmaf(a.x, w.y, acc[0][1]);
      acc[1][0] = fmaf(a.y, w.x, acc[1][0]);
      acc[1][1] = fmaf(a.y, w.y, acc[1][1]);
    }
    if (more) {
      const int nb = pb ^ 1;
      AS_(nb, sk4 + 0, sm) = av2.x; AS_(nb, sk4 + 1, sm) = av2.y;
      AS_(nb, sk4 + 2, sm) = av2.z; AS_(nb, sk4 + 3, sm) = av2.w;
      *reinterpret_cast<float4*>(&WS_(nb, sk, sn4)) = wv2;
      __syncthreads();
      pb = nb;
    }
  }
  #pragma unroll
  for (int j = 0; j < 2; ++j) {
    const int n = bn + tn * 2 + j;
    if (n >= N) continue;
    const float bv = bias[n];
    #pragma unroll
    for (int i = 0; i < 2; ++i) {
      const int m = bm + tm * 2 + i;
      float v = acc[i][j] + bv;
      if (relu) v = fmaxf(v, 0.f);
      out[(size_t)m * N + n] = v;
    }
  }
  #undef AS_
  #undef WS_
}

// ---------------- PREP: nprep(0-799) | sqrtcov(800-807) | RbF(808-823) | l2(824-887)
// | gemm1(888-951) | padinit(952-983) ----------------
__global__ __launch_bounds__(256) void prep_kernel(
    const float* __restrict__ noise, short* __restrict__ nfB,
    const float* __restrict__ R, short* __restrict__ RbF, float* __restrict__ sqrtcov,
    const float* __restrict__ X, const float* __restrict__ W1,
    const float* __restrict__ b1, float* __restrict__ h1,
    const float* __restrict__ W2, const float* __restrict__ W3,
    const float* __restrict__ Wmu, float* __restrict__ l2_part,
    float* __restrict__ rmuP, float* __restrict__ snP) {
  __shared__ float smem[2304 * 2];
  const int blk = blockIdx.x;
  const int tid = threadIdx.x;
  if (blk < 800) {
    // noise -> bf16 MFMA-fragment layout
    const int g = blk * 256 + tid;       // 204800
    const int s = g >> 11;
    const int r = g & 2047;
    const int bt = r >> 6;
    const int ln = r & 63;
    const int cl = ln & 15, grp = ln >> 4;
    const float* src = noise + ((size_t)(s * 512 + bt * 16 + cl) * 64 + grp * 8);
    const float4 a = *reinterpret_cast<const float4*>(src);
    const float4 b = *reinterpret_cast<const float4*>(src + 4);
    const float4 c = *reinterpret_cast<const float4*>(src + 32);
    const float4 d = *reinterpret_cast<const float4*>(src + 36);
    bf16x8* dst = reinterpret_cast<bf16x8*>(nfB);
    const int u = (s * 32 + bt) * 128 + ln;
    dst[u]      = bf16x8{ f2bf(a.x), f2bf(a.y), f2bf(a.z), f2bf(a.w),
                          f2bf(b.x), f2bf(b.y), f2bf(b.z), f2bf(b.w) };
    dst[u + 64] = bf16x8{ f2bf(c.x), f2bf(c.y), f2bf(c.z), f2bf(c.w),
                          f2bf(d.x), f2bf(d.y), f2bf(d.z), f2bf(d.w) };
  } else if (blk < 808) {
    // sqrt(cov_diag): 4 threads per c
    const int idx = (blk - 800) * 256 + tid;   // 0..2047
    const int c = idx >> 2;
    const int zq = (idx & 3) * 16;
    const bool cv = c < Csz;
    const float* src = R + (size_t)c * Zsz + zq;
    float ss = 0.f;
    if (cv) {
      #pragma unroll
      for (int q = 0; q < 4; ++q) {
        const float4 r4 = *reinterpret_cast<const float4*>(src + q * 4);
        ss = fmaf(r4.x, r4.x, ss); ss = fmaf(r4.y, r4.y, ss);
        ss = fmaf(r4.z, r4.z, ss); ss = fmaf(r4.w, r4.w, ss);
      }
    }
    ss += __shfl_xor(ss, 1, 64);
    ss += __shfl_xor(ss, 2, 64);
    if ((idx & 3) == 0 && cv) sqrtcov[c] = sqrtf(1.f + ss);
  } else if (blk < 824) {
    // R -> bf16 MFMA-fragment layout (zero-padded rows >= Csz)
    const int e = (blk - 808) * 256 + tid;     // 0..4095
    const int ct = e >> 7;
    const int f = (e >> 6) & 1;
    const int lane = e & 63;
    const int cl = lane & 15, grp = lane >> 4;
    const int c = ct * 16 + cl;
    bf16x8 out = {0, 0, 0, 0, 0, 0, 0, 0};
    if (c < Csz) {
      const float* src = R + (size_t)c * Zsz + f * 32 + grp * 8;
      const float4 a = *reinterpret_cast<const float4*>(src);
      const float4 b = *reinterpret_cast<const float4*>(src + 4);
      out = bf16x8{ f2bf(a.x), f2bf(a.y), f2bf(a.z), f2bf(a.w),
                    f2bf(b.x), f2bf(b.y), f2bf(b.z), f2bf(b.w) };
    }
    reinterpret_cast<bf16x8*>(RbF)[e] = out;
  } else if (blk < 888) {
    const int bid = blk - 824;
    const int gid = bid * 256 + tid;
    const int stride = 64 * 256;
    float s = 0.f;
    for (int i = gid; i < 65536; i += stride) { float v = W1[i]; s = fmaf(v, v, s); }
    for (int i = gid; i < 32768; i += stride) { float v = W2[i]; s = fmaf(v, v, s); }
    for (int i = gid; i < 65536; i += stride) { float v = W3[i]; s = fmaf(v, v, s); }
    for (int i = gid; i < 128000; i += stride) { float v = Wmu[i]; s = fmaf(v, v, s); }
    const float tot = block_reduce_sum(s, smem);
    if (tid == 0) l2_part[bid] = tot;
  } else if (blk < 952) {
    const int idx = blk - 888;                  // 0..63
    gemm32_body(X, W1, b1, h1, 512, 128, 512, idx & 3, idx >> 2,
                smem, smem + 2304, true);
  } else {
    // pad-init rmuP/snP for n in [496,512) (real 496-499 overwritten by gemm_mu later)
    const int g = (blk - 952) * 256 + tid;      // 0..8191
    const int m = g >> 4;
    const int n = 496 + (g & 15);
    const int idx = ((n >> 4) * 32 + (m >> 4)) * 256
                  + (((n >> 2) & 3) * 16 + (m & 15)) * 4 + (n & 3);
    rmuP[idx] = 0.f;
    snP[idx] = -0.70710678f;   // u=0 regardless -> E=0.5 exactly (log2 = -1)
  }
}

// ---------------- standalone 32x32 GEMM ----------------
template <bool RELU>
__global__ __launch_bounds__(256) void gemm32(
    const float* __restrict__ A, const float* __restrict__ W,
    const float* __restrict__ bias, float* __restrict__ out,
    int M, int N, int K) {
  __shared__ float smem[2304 * 2];
  gemm32_body(A, W, bias, out, M, N, K, blockIdx.x, blockIdx.y,
              smem, smem + 2304, RELU);
}

// ---------------- MU GEMM: -> indiv_prob, CE partials, fragment-ordered rmuP/snP ----------------
// snP holds snC = sign(2y-1) * (-1/sqrt(2)):  u = (acc+rmu)*snC
__global__ __launch_bounds__(256) void gemm32_mu(
    const float* __restrict__ A, const float* __restrict__ W,
    const float* __restrict__ bias, const float* __restrict__ Y,
    const float* __restrict__ sqrtcov,
    float* __restrict__ out_prob, float* __restrict__ rmuP, float* __restrict__ snP,
    float* __restrict__ ce_part, int M, int N, int K) {
  __shared__ float As[2][32][36];
  __shared__ float Ws[2][32][36];
  const int tid = threadIdx.x;
  const int bn = blockIdx.x * 32, bm = blockIdx.y * 32;
  const int sm = tid >> 3, sk4 = (tid & 7) * 4;
  const int sk = tid >> 3, sn4 = (tid & 7) * 4;
  const int tn = tid & 15, tm = tid >> 4;

  auto loadW = [&](int kt, float4& wv) {
    const float* wrow = W + (size_t)(kt + sk) * N;
    const int nn = bn + sn4;
    if (nn + 3 < N) wv = *reinterpret_cast<const float4*>(wrow + nn);
    else {
      wv.x = (nn + 0 < N) ? wrow[nn + 0] : 0.f;
      wv.y = (nn + 1 < N) ? wrow[nn + 1] : 0.f;
      wv.z = (nn + 2 < N) ? wrow[nn + 2] : 0.f;
      wv.w = (nn + 3 < N) ? wrow[nn + 3] : 0.f;
    }
  };
  {
    float4 av = *reinterpret_cast<const float4*>(A + (size_t)(bm + sm) * K + sk4);
    float4 wv; loadW(0, wv);
    As[0][sk4 + 0][sm] = av.x; As[0][sk4 + 1][sm] = av.y;
    As[0][sk4 + 2][sm] = av.z; As[0][sk4 + 3][sm] = av.w;
    *reinterpret_cast<float4*>(&Ws[0][sk][sn4]) = wv;
  }
  __syncthreads();
  float acc[2][2] = {};
  int pb = 0;
  for (int kt = 0; kt < K; kt += 32) {
    const bool more = (kt + 32) < K;
    float4 av2, wv2;
    if (more) {
      av2 = *reinterpret_cast<const float4*>(A + (size_t)(bm + sm) * K + kt + 32 + sk4);
      loadW(kt + 32, wv2);
    }
    #pragma unroll
    for (int k = 0; k < 32; ++k) {
      const float2 a = *reinterpret_cast<const float2*>(&As[pb][k][tm * 2]);
      const float2 w = *reinterpret_cast<const float2*>(&Ws[pb][k][tn * 2]);
      acc[0][0] = fmaf(a.x, w.x, acc[0][0]);
      acc[0][1] = fmaf(a.x, w.y, acc[0][1]);
      acc[1][0] = fmaf(a.y, w.x, acc[1][0]);
      acc[1][1] = fmaf(a.y, w.y, acc[1][1]);
    }
    if (more) {
      const int nb = pb ^ 1;
      As[nb][sk4 + 0][sm] = av2.x; As[nb][sk4 + 1][sm] = av2.y;
      As[nb][sk4 + 2][sm] = av2.z; As[nb][sk4 + 3][sm] = av2.w;
      *reinterpret_cast<float4*>(&Ws[nb][sk][sn4]) = wv2;
      __syncthreads();
      pb = nb;
    }
  }
  float ce2[2] = {0.f, 0.f};
  #pragma unroll
  for (int i = 0; i < 2; ++i) {
    const int m = bm + tm * 2 + i;
    #pragma unroll
    for (int j = 0; j < 2; ++j) {
      const int n = bn + tn * 2 + j;
      if (n < N) {
        const float v = acc[i][j] + bias[n];
        const float sp = __builtin_amdgcn_rcpf(1.f + __expf(-1.70169f * v));
        const float p = fmaf(sp, 1.f - EPS1f, 0.5f * EPS1f);
        const float q = fmaf(1.f - sp, 1.f - EPS1f, 0.5f * EPS1f);
        const float y = Y[(size_t)m * N + n];
        out_prob[(size_t)m * N + n] = p;
        ce2[i] += __logf((y > 0.5f) ? p : q);
        // fragment-ordered: idx = (ct*32+bt)*256 + lane*4 + j
        const int idx = (((n >> 4) * 32 + (m >> 4)) << 8)
                      + ((((n >> 2) & 3) * 16 + (m & 15)) << 2) + (n & 3);
        rmuP[idx] = v * sqrtcov[n];
        snP[idx] = (y > 0.5f) ? -0.70710678f : 0.70710678f;
      }
    }
  }
  #pragma unroll
  for (int off = 1; off < 16; off <<= 1) {
    ce2[0] += __shfl_xor(ce2[0], off, 64);
    ce2[1] += __shfl_xor(ce2[1], off, 64);
  }
  if (tn == 0) {
    const int m0 = bm + tm * 2;
    ce_part[(size_t)blockIdx.x * Bsz + m0] = ce2[0];
    ce_part[(size_t)blockIdx.x * Bsz + m0 + 1] = ce2[1];
  }
}

// ---------------- HOT: c-inner MFMA + probit log-likelihood, 8 c-tiles/wave ----------------
// grid = 100 s x 16 btg x 2 chh = 3200 blocks (12800 waves -> sustained ~8 waves/SIMD).
// log2-domain accumulation; halved A&S coeffs (0.5 folded); sign premultiplied into snP.
__global__ __launch_bounds__(256) void logprob_s3(
    const short* __restrict__ nfB, const short* __restrict__ RbF,
    const float* __restrict__ rmuP, const float* __restrict__ snP,
    float* __restrict__ lp4) {
  const int blk = blockIdx.x;          // chh + 2*btg + 32*s
  const int chh = blk & 1;
  const int btg = (blk >> 1) & 15;
  const int s = blk >> 5;
  const int wid = threadIdx.x >> 6;
  const int lane = threadIdx.x & 63;
  const int bt = btg * 2 + (wid & 1);
  const int chq = chh * 2 + (wid >> 1);   // 0..3, 8 c-tiles each

  const bf16x8* nf = reinterpret_cast<const bf16x8*>(nfB);
  const int nbase = (s * 32 + bt) * 128 + lane;
  const bf16x8 n0 = nf[nbase];               // resident noise frag
  const bf16x8 n1 = nf[nbase + 64];
  const bf16x8* rf = reinterpret_cast<const bf16x8*>(RbF);

  float lpl = 0.f;                           // log2 domain
  #pragma unroll 2
  for (int t = 0; t < 8; ++t) {
    const int ct = chq * 8 + t;
    const bf16x8 Rf0 = rf[(ct * 2 + 0) * 64 + lane];
    const bf16x8 Rf1 = rf[(ct * 2 + 1) * 64 + lane];
    f32x4 acc = {0.f, 0.f, 0.f, 0.f};
    acc = __builtin_amdgcn_mfma_f32_16x16x32_bf16(Rf0, n0, acc, 0, 0, 0);
    acc = __builtin_amdgcn_mfma_f32_16x16x32_bf16(Rf1, n1, acc, 0, 0, 0);
    const int fb = (ct * 32 + bt) * 256 + lane * 4;
    const float4 rmu4 = *reinterpret_cast<const float4*>(rmuP + fb);
    const float4 sn4  = *reinterpret_cast<const float4*>(snP + fb);
    // batched 4-wide probit: stage-by-stage for back-to-back trans issue
    float u[4], sc[4], p[4], e[4];
    u[0] = (acc[0] + rmu4.x) * sn4.x;
    u[1] = (acc[1] + rmu4.y) * sn4.y;
    u[2] = (acc[2] + rmu4.z) * sn4.z;
    u[3] = (acc[3] + rmu4.w) * sn4.w;
    #pragma unroll
    for (int i = 0; i < 4; ++i)
      sc[i] = __builtin_amdgcn_rcpf(fmaf(0.3275911f, fabsf(u[i]), 1.f));
    #pragma unroll
    for (int i = 0; i < 4; ++i) {
      float q = fmaf(0.5307027145f, sc[i], -0.7265760135f);   // halved A&S coeffs
      q = fmaf(q, sc[i], 0.7107068705f);
      q = fmaf(q, sc[i], -0.142248368f);
      q = fmaf(q, sc[i], 0.127414796f);
      p[i] = q * sc[i];                                        // = 0.5*erfc_poly
    }
    #pragma unroll
    for (int i = 0; i < 4; ++i) e[i] = __expf(-u[i] * u[i]);
    #pragma unroll
    for (int i = 0; i < 4; ++i) {
      const float f = p[i] * e[i];                // Phi for u>=0
      const float Phi = (u[i] < 0.f) ? 1.f - f : f;
      lpl += __log2f(fmaf(Phi, 1.f - EPS1f, 0.5f * EPS1f));
    }
  }
  lpl += __shfl_xor(lpl, 16, 64);
  lpl += __shfl_xor(lpl, 32, 64);
  if (lane < 16) {
    // pad c's (500-511, all in chq 3) each contribute exactly -1.0 in log2
    const float fix = (chq == 3) ? 12.0f : 0.f;
    lp4[(size_t)(chq * Ssz + s) * 512 + bt * 16 + lane] =
        (lpl + fix) * 0.69314718055994531f;
  }
}

// ---------------- per-b log-sum-exp over S (4-way s-parallel, 4-chunk fused) ----------------
__global__ __launch_bounds__(256) void nll_kernel(const float* __restrict__ lp4,
                                                  float* __restrict__ nll_b) {
  __shared__ float sm[4][64], sse[4][64];
  const int bl = threadIdx.x & 63;
  const int sc = threadIdx.x >> 6;
  const int b = blockIdx.x * 64 + bl;
  float m = -3.0e38f, se = 0.f;
  for (int s = sc * 25; s < sc * 25 + 25; ++s) {
    const float v = lp4[(size_t)s * 512 + b]
                  + lp4[(size_t)(Ssz + s) * 512 + b]
                  + lp4[(size_t)(2 * Ssz + s) * 512 + b]
                  + lp4[(size_t)(3 * Ssz + s) * 512 + b];
    const float mn = fmaxf(m, v);
    se = se * __expf(m - mn) + __expf(v - mn);
    m = mn;
  }
  sm[sc][bl] = m; sse[sc][bl] = se;
  __syncthreads();
  if (sc == 0) {
    float M = sm[0][bl];
    #pragma unroll
    for (int i = 1; i < 4; ++i) M = fmaxf(M, sm[i][bl]);
    float SE = 0.f;
    #pragma unroll
    for (int i = 0; i < 4; ++i) SE += sse[i][bl] * __expf(sm[i][bl] - M);
    nll_b[b] = -__logf(SE * (1.f / (float)Ssz)) - M;
  }
}

// ---------------- final scalars ----------------
__global__ __launch_bounds__(256) void finals_kernel(
    const float* __restrict__ nll_b, const float* __restrict__ ce_part,
    const float* __restrict__ l2_part, int nparts, float* __restrict__ out4) {
  __shared__ float red[4];
  const int t = threadIdx.x;
  const float snll = block_reduce_sum(nll_b[t] + nll_b[t + 256], red);
  float ce = 0.f;
  #pragma unroll
  for (int i = 0; i < 32; ++i) ce += ce_part[i * 256 + t];
  const float sce = block_reduce_sum(ce, red);
  const float sl2 = block_reduce_sum((t < nparts) ? l2_part[t] : 0.f, red);
  if (t == 0) {
    const float nll = snll / (float)Bsz;
    const float marg = -sce / (float)Bsz;
    const float l2v = WDf * sl2;
    out4[0] = nll;
    out4[1] = marg;
    out4[2] = l2v;
    out4[3] = l2v + nll;
  }
}

// ---------------- launch ----------------
extern "C" void kernel_launch(void* const* d_in, const int* in_sizes, int n_in,
                              void* d_out, int out_size, void* d_ws, size_t ws_size,
                              hipStream_t stream) {
  const float* X = (const float*)d_in[0];
  const float* Y = (const float*)d_in[1];
  const float* noise = (const float*)d_in[2];
  const float* W1 = (const float*)d_in[3];
  const float* b1 = (const float*)d_in[4];
  const float* W2 = (const float*)d_in[5];
  const float* b2 = (const float*)d_in[6];
  const float* W3 = (const float*)d_in[7];
  const float* b3 = (const float*)d_in[8];
  const float* Wmu = (const float*)d_in[9];
  const float* bmu = (const float*)d_in[10];
  const float* rss = (const float*)d_in[11];

  float* ws = (float*)d_ws;
  float* h1 = ws;                         // 512*128
  float* h2 = h1 + 65536;                 // 512*256
  float* feat = h2 + 131072;              // 512*256   (ends 327680)
  float* B0 = ws + 327680;
  float* sqrtcov = B0;                    // 512
  float* rmuP = sqrtcov + 512;            // 512*512 fragment-ordered
  float* snP = rmuP + 262144;             // 512*512 fragment-ordered (snC = +/- 1/sqrt2)
  float* ce_part = snP + 262144;          // 16*512
  float* nll_b = ce_part + 8192;          // 512
  float* l2_part = nll_b + 512;           // 128
  float* lp4 = l2_part + 128;             // 4*100*512 = 204800
  short* RbF = (short*)(lp4 + 204800);    // 4096 entries * 8 shorts
  short* nfB = RbF + 32768;               // 100*32*128*8 shorts

  float* out_prob = (float*)d_out;
  float* out4 = out_prob + (size_t)Bsz * Csz;

  prep_kernel<<<dim3(984), 256, 0, stream>>>(noise, nfB, rss, RbF, sqrtcov,
                                             X, W1, b1, h1, W2, W3, Wmu, l2_part,
                                             rmuP, snP);

  gemm32<true><<<dim3(8, 16), 256, 0, stream>>>(h1, W2, b2, h2, 512, 256, 128);
  gemm32<true><<<dim3(8, 16), 256, 0, stream>>>(h2, W3, b3, feat, 512, 256, 256);
  gemm32_mu<<<dim3(16, 16), 256, 0, stream>>>(feat, Wmu, bmu, Y, sqrtcov,
                                              out_prob, rmuP, snP, ce_part, 512, 500, 256);

  logprob_s3<<<dim3(3200), 256, 0, stream>>>(nfB, RbF, rmuP, snP, lp4);
  nll_kernel<<<dim3(8), 256, 0, stream>>>(lp4, nll_b);

  finals_kernel<<<dim3(1), 256, 0, stream>>>(nll_b, ce_part, l2_part, 64, out4);
}

// Round 15
// 72.174 us; speedup vs baseline: 2.3810x; 1.0210x over previous
//
#include <hip/hip_runtime.h>
#include <cstddef>

#define EPS1f 1e-6f
#define WDf   1e-5f

constexpr int Bsz = 512, Csz = 500, Zsz = 64, Ssz = 100;

typedef short bf16x8 __attribute__((ext_vector_type(8)));
typedef float f32x4 __attribute__((ext_vector_type(4)));

__device__ inline short f2bf(float f) {
  union { float f; unsigned u; } v; v.f = f;
  unsigned r = (v.u + 0x7fffu + ((v.u >> 16) & 1u)) >> 16;   // RNE
  return (short)r;
}

__device__ inline float block_reduce_sum(float v, float* red) {
  #pragma unroll
  for (int off = 32; off > 0; off >>= 1) v += __shfl_down(v, off, 64);
  const int lane = threadIdx.x & 63, wid = threadIdx.x >> 6;
  if (lane == 0) red[wid] = v;
  __syncthreads();
  float r = 0.f;
  if (threadIdx.x == 0) {
    const int nw = blockDim.x >> 6;
    for (int i = 0; i < nw; ++i) r += red[i];
  }
  __syncthreads();
  return r;   // valid in thread 0 only
}

// ---------------- 32x32 double-buffered GEMM body ----------------
__device__ __forceinline__ void gemm32_body(
    const float* __restrict__ A, const float* __restrict__ W,
    const float* __restrict__ bias, float* __restrict__ out,
    int M, int N, int K, int bn0, int bm0, float* As_, float* Ws_, bool relu) {
  const int tid = threadIdx.x;
  const int bn = bn0 * 32, bm = bm0 * 32;
  const int sm = tid >> 3, sk4 = (tid & 7) * 4;
  const int sk = tid >> 3, sn4 = (tid & 7) * 4;
  const int tn = tid & 15, tm = tid >> 4;
  #define AS_(b, k, m) As_[(b) * 1152 + (k) * 36 + (m)]
  #define WS_(b, k, n) Ws_[(b) * 1152 + (k) * 36 + (n)]
  auto loadW = [&](int kt, float4& wv) {
    const float* wrow = W + (size_t)(kt + sk) * N;
    const int nn = bn + sn4;
    if (nn + 3 < N) wv = *reinterpret_cast<const float4*>(wrow + nn);
    else {
      wv.x = (nn + 0 < N) ? wrow[nn + 0] : 0.f;
      wv.y = (nn + 1 < N) ? wrow[nn + 1] : 0.f;
      wv.z = (nn + 2 < N) ? wrow[nn + 2] : 0.f;
      wv.w = (nn + 3 < N) ? wrow[nn + 3] : 0.f;
    }
  };
  {
    float4 av = *reinterpret_cast<const float4*>(A + (size_t)(bm + sm) * K + sk4);
    float4 wv; loadW(0, wv);
    AS_(0, sk4 + 0, sm) = av.x; AS_(0, sk4 + 1, sm) = av.y;
    AS_(0, sk4 + 2, sm) = av.z; AS_(0, sk4 + 3, sm) = av.w;
    *reinterpret_cast<float4*>(&WS_(0, sk, sn4)) = wv;
  }
  __syncthreads();
  float acc[2][2] = {};
  int pb = 0;
  for (int kt = 0; kt < K; kt += 32) {
    const bool more = (kt + 32) < K;
    float4 av2, wv2;
    if (more) {
      av2 = *reinterpret_cast<const float4*>(A + (size_t)(bm + sm) * K + kt + 32 + sk4);
      loadW(kt + 32, wv2);
    }
    #pragma unroll
    for (int k = 0; k < 32; ++k) {
      const float2 a = *reinterpret_cast<const float2*>(&AS_(pb, k, tm * 2));
      const float2 w = *reinterpret_cast<const float2*>(&WS_(pb, k, tn * 2));
      acc[0][0] = fmaf(a.x, w.x, acc[0][0]);
      acc[0][1] = fmaf(a.x, w.y, acc[0][1]);
      acc[1][0] = fmaf(a.y, w.x, acc[1][0]);
      acc[1][1] = fmaf(a.y, w.y, acc[1][1]);
    }
    if (more) {
      const int nb = pb ^ 1;
      AS_(nb, sk4 + 0, sm) = av2.x; AS_(nb, sk4 + 1, sm) = av2.y;
      AS_(nb, sk4 + 2, sm) = av2.z; AS_(nb, sk4 + 3, sm) = av2.w;
      *reinterpret_cast<float4*>(&WS_(nb, sk, sn4)) = wv2;
      __syncthreads();
      pb = nb;
    }
  }
  #pragma unroll
  for (int j = 0; j < 2; ++j) {
    const int n = bn + tn * 2 + j;
    if (n >= N) continue;
    const float bv = bias[n];
    #pragma unroll
    for (int i = 0; i < 2; ++i) {
      const int m = bm + tm * 2 + i;
      float v = acc[i][j] + bv;
      if (relu) v = fmaxf(v, 0.f);
      out[(size_t)m * N + n] = v;
    }
  }
  #undef AS_
  #undef WS_
}

// ---------------- PREP: nprep(0-799) | sqrtcov(800-807) | RbF(808-823) | l2(824-887)
// | gemm1(888-951) | padinit(952-983) ----------------
__global__ __launch_bounds__(256) void prep_kernel(
    const float* __restrict__ noise, short* __restrict__ nfB,
    const float* __restrict__ R, short* __restrict__ RbF, float* __restrict__ sqrtcov,
    const float* __restrict__ X, const float* __restrict__ W1,
    const float* __restrict__ b1, float* __restrict__ h1,
    const float* __restrict__ W2, const float* __restrict__ W3,
    const float* __restrict__ Wmu, float* __restrict__ l2_part,
    float* __restrict__ rsP, float* __restrict__ snP) {
  __shared__ float smem[2304 * 2];
  const int blk = blockIdx.x;
  const int tid = threadIdx.x;
  if (blk < 800) {
    // noise -> bf16 MFMA-fragment layout
    const int g = blk * 256 + tid;       // 204800
    const int s = g >> 11;
    const int r = g & 2047;
    const int bt = r >> 6;
    const int ln = r & 63;
    const int cl = ln & 15, grp = ln >> 4;
    const float* src = noise + ((size_t)(s * 512 + bt * 16 + cl) * 64 + grp * 8);
    const float4 a = *reinterpret_cast<const float4*>(src);
    const float4 b = *reinterpret_cast<const float4*>(src + 4);
    const float4 c = *reinterpret_cast<const float4*>(src + 32);
    const float4 d = *reinterpret_cast<const float4*>(src + 36);
    bf16x8* dst = reinterpret_cast<bf16x8*>(nfB);
    const int u = (s * 32 + bt) * 128 + ln;
    dst[u]      = bf16x8{ f2bf(a.x), f2bf(a.y), f2bf(a.z), f2bf(a.w),
                          f2bf(b.x), f2bf(b.y), f2bf(b.z), f2bf(b.w) };
    dst[u + 64] = bf16x8{ f2bf(c.x), f2bf(c.y), f2bf(c.z), f2bf(c.w),
                          f2bf(d.x), f2bf(d.y), f2bf(d.z), f2bf(d.w) };
  } else if (blk < 808) {
    // sqrt(cov_diag): 4 threads per c
    const int idx = (blk - 800) * 256 + tid;   // 0..2047
    const int c = idx >> 2;
    const int zq = (idx & 3) * 16;
    const bool cv = c < Csz;
    const float* src = R + (size_t)c * Zsz + zq;
    float ss = 0.f;
    if (cv) {
      #pragma unroll
      for (int q = 0; q < 4; ++q) {
        const float4 r4 = *reinterpret_cast<const float4*>(src + q * 4);
        ss = fmaf(r4.x, r4.x, ss); ss = fmaf(r4.y, r4.y, ss);
        ss = fmaf(r4.z, r4.z, ss); ss = fmaf(r4.w, r4.w, ss);
      }
    }
    ss += __shfl_xor(ss, 1, 64);
    ss += __shfl_xor(ss, 2, 64);
    if ((idx & 3) == 0 && cv) sqrtcov[c] = sqrtf(1.f + ss);
  } else if (blk < 824) {
    // R -> bf16 MFMA-fragment layout (zero-padded rows >= Csz)
    const int e = (blk - 808) * 256 + tid;     // 0..4095
    const int ct = e >> 7;
    const int f = (e >> 6) & 1;
    const int lane = e & 63;
    const int cl = lane & 15, grp = lane >> 4;
    const int c = ct * 16 + cl;
    bf16x8 out = {0, 0, 0, 0, 0, 0, 0, 0};
    if (c < Csz) {
      const float* src = R + (size_t)c * Zsz + f * 32 + grp * 8;
      const float4 a = *reinterpret_cast<const float4*>(src);
      const float4 b = *reinterpret_cast<const float4*>(src + 4);
      out = bf16x8{ f2bf(a.x), f2bf(a.y), f2bf(a.z), f2bf(a.w),
                    f2bf(b.x), f2bf(b.y), f2bf(b.z), f2bf(b.w) };
    }
    reinterpret_cast<bf16x8*>(RbF)[e] = out;
  } else if (blk < 888) {
    const int bid = blk - 824;
    const int gid = bid * 256 + tid;
    const int stride = 64 * 256;
    float s = 0.f;
    for (int i = gid; i < 65536; i += stride) { float v = W1[i]; s = fmaf(v, v, s); }
    for (int i = gid; i < 32768; i += stride) { float v = W2[i]; s = fmaf(v, v, s); }
    for (int i = gid; i < 65536; i += stride) { float v = W3[i]; s = fmaf(v, v, s); }
    for (int i = gid; i < 128000; i += stride) { float v = Wmu[i]; s = fmaf(v, v, s); }
    const float tot = block_reduce_sum(s, smem);
    if (tid == 0) l2_part[bid] = tot;
  } else if (blk < 952) {
    const int idx = blk - 888;                  // 0..63
    gemm32_body(X, W1, b1, h1, 512, 128, 512, idx & 3, idx >> 2,
                smem, smem + 2304, true);
  } else {
    // pad-init rsP/snP for n in [496,512) (real 496-499 overwritten by gemm_mu later)
    const int g = (blk - 952) * 256 + tid;      // 0..8191
    const int m = g >> 4;
    const int n = 496 + (g & 15);
    const int idx = ((n >> 4) * 32 + (m >> 4)) * 256
                  + (((n >> 2) & 3) * 16 + (m & 15)) * 4 + (n & 3);
    rsP[idx] = 0.f;                 // u = acc*sn + 0; acc=0 (zero R rows) -> u=0 -> E=0.5
    snP[idx] = -0.70710678f;
  }
}

// ---------------- standalone 32x32 GEMM ----------------
template <bool RELU>
__global__ __launch_bounds__(256) void gemm32(
    const float* __restrict__ A, const float* __restrict__ W,
    const float* __restrict__ bias, float* __restrict__ out,
    int M, int N, int K) {
  __shared__ float smem[2304 * 2];
  gemm32_body(A, W, bias, out, M, N, K, blockIdx.x, blockIdx.y,
              smem, smem + 2304, RELU);
}

// ---------------- MU GEMM: -> indiv_prob, CE partials, fragment-ordered rsP/snP ----------------
// snP = sign(2y-1)*(-1/sqrt2);  rsP = rmu*snP  ->  u = fmaf(acc, sn, rs)
__global__ __launch_bounds__(256) void gemm32_mu(
    const float* __restrict__ A, const float* __restrict__ W,
    const float* __restrict__ bias, const float* __restrict__ Y,
    const float* __restrict__ sqrtcov,
    float* __restrict__ out_prob, float* __restrict__ rsP, float* __restrict__ snP,
    float* __restrict__ ce_part, int M, int N, int K) {
  __shared__ float As[2][32][36];
  __shared__ float Ws[2][32][36];
  const int tid = threadIdx.x;
  const int bn = blockIdx.x * 32, bm = blockIdx.y * 32;
  const int sm = tid >> 3, sk4 = (tid & 7) * 4;
  const int sk = tid >> 3, sn4 = (tid & 7) * 4;
  const int tn = tid & 15, tm = tid >> 4;

  auto loadW = [&](int kt, float4& wv) {
    const float* wrow = W + (size_t)(kt + sk) * N;
    const int nn = bn + sn4;
    if (nn + 3 < N) wv = *reinterpret_cast<const float4*>(wrow + nn);
    else {
      wv.x = (nn + 0 < N) ? wrow[nn + 0] : 0.f;
      wv.y = (nn + 1 < N) ? wrow[nn + 1] : 0.f;
      wv.z = (nn + 2 < N) ? wrow[nn + 2] : 0.f;
      wv.w = (nn + 3 < N) ? wrow[nn + 3] : 0.f;
    }
  };
  {
    float4 av = *reinterpret_cast<const float4*>(A + (size_t)(bm + sm) * K + sk4);
    float4 wv; loadW(0, wv);
    As[0][sk4 + 0][sm] = av.x; As[0][sk4 + 1][sm] = av.y;
    As[0][sk4 + 2][sm] = av.z; As[0][sk4 + 3][sm] = av.w;
    *reinterpret_cast<float4*>(&Ws[0][sk][sn4]) = wv;
  }
  __syncthreads();
  float acc[2][2] = {};
  int pb = 0;
  for (int kt = 0; kt < K; kt += 32) {
    const bool more = (kt + 32) < K;
    float4 av2, wv2;
    if (more) {
      av2 = *reinterpret_cast<const float4*>(A + (size_t)(bm + sm) * K + kt + 32 + sk4);
      loadW(kt + 32, wv2);
    }
    #pragma unroll
    for (int k = 0; k < 32; ++k) {
      const float2 a = *reinterpret_cast<const float2*>(&As[pb][k][tm * 2]);
      const float2 w = *reinterpret_cast<const float2*>(&Ws[pb][k][tn * 2]);
      acc[0][0] = fmaf(a.x, w.x, acc[0][0]);
      acc[0][1] = fmaf(a.x, w.y, acc[0][1]);
      acc[1][0] = fmaf(a.y, w.x, acc[1][0]);
      acc[1][1] = fmaf(a.y, w.y, acc[1][1]);
    }
    if (more) {
      const int nb = pb ^ 1;
      As[nb][sk4 + 0][sm] = av2.x; As[nb][sk4 + 1][sm] = av2.y;
      As[nb][sk4 + 2][sm] = av2.z; As[nb][sk4 + 3][sm] = av2.w;
      *reinterpret_cast<float4*>(&Ws[nb][sk][sn4]) = wv2;
      __syncthreads();
      pb = nb;
    }
  }
  float ce2[2] = {0.f, 0.f};
  #pragma unroll
  for (int i = 0; i < 2; ++i) {
    const int m = bm + tm * 2 + i;
    #pragma unroll
    for (int j = 0; j < 2; ++j) {
      const int n = bn + tn * 2 + j;
      if (n < N) {
        const float v = acc[i][j] + bias[n];
        const float sp = __builtin_amdgcn_rcpf(1.f + __expf(-1.70169f * v));
        const float p = fmaf(sp, 1.f - EPS1f, 0.5f * EPS1f);
        const float q = fmaf(1.f - sp, 1.f - EPS1f, 0.5f * EPS1f);
        const float y = Y[(size_t)m * N + n];
        out_prob[(size_t)m * N + n] = p;
        ce2[i] += __logf((y > 0.5f) ? p : q);
        // fragment-ordered: idx = (ct*32+bt)*256 + lane*4 + j
        const int idx = (((n >> 4) * 32 + (m >> 4)) << 8)
                      + ((((n >> 2) & 3) * 16 + (m & 15)) << 2) + (n & 3);
        const float snc = (y > 0.5f) ? -0.70710678f : 0.70710678f;
        snP[idx] = snc;
        rsP[idx] = v * sqrtcov[n] * snc;
      }
    }
  }
  #pragma unroll
  for (int off = 1; off < 16; off <<= 1) {
    ce2[0] += __shfl_xor(ce2[0], off, 64);
    ce2[1] += __shfl_xor(ce2[1], off, 64);
  }
  if (tn == 0) {
    const int m0 = bm + tm * 2;
    ce_part[(size_t)blockIdx.x * Bsz + m0] = ce2[0];
    ce_part[(size_t)blockIdx.x * Bsz + m0 + 1] = ce2[1];
  }
}

// ---------------- HOT: c-inner MFMA + probit log-likelihood, fully unrolled ----------------
// grid = 100 s x 16 btg x 2 chh = 3200 blocks. Full unroll: compiler software-pipelines
// all 32 operand loads across the 8-iter body (L2-latency cover).
__global__ void logprob_s3(
    const short* __restrict__ nfB, const short* __restrict__ RbF,
    const float* __restrict__ rsP, const float* __restrict__ snP,
    float* __restrict__ lp4) {
  const int blk = blockIdx.x;          // chh + 2*btg + 32*s
  const int chh = blk & 1;
  const int btg = (blk >> 1) & 15;
  const int s = blk >> 5;
  const int wid = threadIdx.x >> 6;
  const int lane = threadIdx.x & 63;
  const int bt = btg * 2 + (wid & 1);
  const int chq = chh * 2 + (wid >> 1);   // 0..3, 8 c-tiles each

  const bf16x8* nf = reinterpret_cast<const bf16x8*>(nfB);
  const int nbase = (s * 32 + bt) * 128 + lane;
  const bf16x8 n0 = nf[nbase];               // resident noise frag
  const bf16x8 n1 = nf[nbase + 64];
  const bf16x8* rf = reinterpret_cast<const bf16x8*>(RbF);

  float lpl = 0.f;                           // log2 domain
  #pragma unroll
  for (int t = 0; t < 8; ++t) {
    const int ct = chq * 8 + t;
    const bf16x8 Rf0 = rf[(ct * 2 + 0) * 64 + lane];
    const bf16x8 Rf1 = rf[(ct * 2 + 1) * 64 + lane];
    f32x4 acc = {0.f, 0.f, 0.f, 0.f};
    acc = __builtin_amdgcn_mfma_f32_16x16x32_bf16(Rf0, n0, acc, 0, 0, 0);
    acc = __builtin_amdgcn_mfma_f32_16x16x32_bf16(Rf1, n1, acc, 0, 0, 0);
    const int fb = (ct * 32 + bt) * 256 + lane * 4;
    const float4 rs4 = *reinterpret_cast<const float4*>(rsP + fb);
    const float4 sn4 = *reinterpret_cast<const float4*>(snP + fb);
    // batched 4-wide probit
    float u[4], sc[4], p[4], e[4];
    u[0] = fmaf(acc[0], sn4.x, rs4.x);
    u[1] = fmaf(acc[1], sn4.y, rs4.y);
    u[2] = fmaf(acc[2], sn4.z, rs4.z);
    u[3] = fmaf(acc[3], sn4.w, rs4.w);
    #pragma unroll
    for (int i = 0; i < 4; ++i)
      sc[i] = __builtin_amdgcn_rcpf(fmaf(0.3275911f, fabsf(u[i]), 1.f));
    #pragma unroll
    for (int i = 0; i < 4; ++i) {
      float q = fmaf(0.5307027145f, sc[i], -0.7265760135f);   // halved A&S coeffs
      q = fmaf(q, sc[i], 0.7107068705f);
      q = fmaf(q, sc[i], -0.142248368f);
      q = fmaf(q, sc[i], 0.127414796f);
      p[i] = q * sc[i];                                        // = 0.5*erfc_poly
    }
    #pragma unroll
    for (int i = 0; i < 4; ++i) e[i] = __expf(-u[i] * u[i]);
    #pragma unroll
    for (int i = 0; i < 4; ++i) {
      const float f = p[i] * e[i];                // Phi for u>=0
      const float Phi = (u[i] < 0.f) ? 1.f - f : f;
      lpl += __log2f(fmaf(Phi, 1.f - EPS1f, 0.5f * EPS1f));
    }
  }
  lpl += __shfl_xor(lpl, 16, 64);
  lpl += __shfl_xor(lpl, 32, 64);
  if (lane < 16) {
    // pad c's (500-511, all in chq 3) each contribute exactly -1.0 in log2
    const float fix = (chq == 3) ? 12.0f : 0.f;
    lp4[(size_t)(chq * Ssz + s) * 512 + bt * 16 + lane] =
        (lpl + fix) * 0.69314718055994531f;
  }
}

// ---------------- per-b log-sum-exp over S (4-way s-parallel, 4-chunk fused) ----------------
__global__ __launch_bounds__(256) void nll_kernel(const float* __restrict__ lp4,
                                                  float* __restrict__ nll_b) {
  __shared__ float sm[4][64], sse[4][64];
  const int bl = threadIdx.x & 63;
  const int sc = threadIdx.x >> 6;
  const int b = blockIdx.x * 64 + bl;
  float m = -3.0e38f, se = 0.f;
  for (int s = sc * 25; s < sc * 25 + 25; ++s) {
    const float v = lp4[(size_t)s * 512 + b]
                  + lp4[(size_t)(Ssz + s) * 512 + b]
                  + lp4[(size_t)(2 * Ssz + s) * 512 + b]
                  + lp4[(size_t)(3 * Ssz + s) * 512 + b];
    const float mn = fmaxf(m, v);
    se = se * __expf(m - mn) + __expf(v - mn);
    m = mn;
  }
  sm[sc][bl] = m; sse[sc][bl] = se;
  __syncthreads();
  if (sc == 0) {
    float M = sm[0][bl];
    #pragma unroll
    for (int i = 1; i < 4; ++i) M = fmaxf(M, sm[i][bl]);
    float SE = 0.f;
    #pragma unroll
    for (int i = 0; i < 4; ++i) SE += sse[i][bl] * __expf(sm[i][bl] - M);
    nll_b[b] = -__logf(SE * (1.f / (float)Ssz)) - M;
  }
}

// ---------------- final scalars ----------------
__global__ __launch_bounds__(256) void finals_kernel(
    const float* __restrict__ nll_b, const float* __restrict__ ce_part,
    const float* __restrict__ l2_part, int nparts, float* __restrict__ out4) {
  __shared__ float red[4];
  const int t = threadIdx.x;
  const float snll = block_reduce_sum(nll_b[t] + nll_b[t + 256], red);
  float ce = 0.f;
  #pragma unroll
  for (int i = 0; i < 32; ++i) ce += ce_part[i * 256 + t];
  const float sce = block_reduce_sum(ce, red);
  const float sl2 = block_reduce_sum((t < nparts) ? l2_part[t] : 0.f, red);
  if (t == 0) {
    const float nll = snll / (float)Bsz;
    const float marg = -sce / (float)Bsz;
    const float l2v = WDf * sl2;
    out4[0] = nll;
    out4[1] = marg;
    out4[2] = l2v;
    out4[3] = l2v + nll;
  }
}

// ---------------- launch ----------------
extern "C" void kernel_launch(void* const* d_in, const int* in_sizes, int n_in,
                              void* d_out, int out_size, void* d_ws, size_t ws_size,
                              hipStream_t stream) {
  const float* X = (const float*)d_in[0];
  const float* Y = (const float*)d_in[1];
  const float* noise = (const float*)d_in[2];
  const float* W1 = (const float*)d_in[3];
  const float* b1 = (const float*)d_in[4];
  const float* W2 = (const float*)d_in[5];
  const float* b2 = (const float*)d_in[6];
  const float* W3 = (const float*)d_in[7];
  const float* b3 = (const float*)d_in[8];
  const float* Wmu = (const float*)d_in[9];
  const float* bmu = (const float*)d_in[10];
  const float* rss = (const float*)d_in[11];

  float* ws = (float*)d_ws;
  float* h1 = ws;                         // 512*128
  float* h2 = h1 + 65536;                 // 512*256
  float* feat = h2 + 131072;              // 512*256   (ends 327680)
  float* B0 = ws + 327680;
  float* sqrtcov = B0;                    // 512
  float* rsP = sqrtcov + 512;             // 512*512 fragment-ordered (rmu*snC)
  float* snP = rsP + 262144;              // 512*512 fragment-ordered (snC)
  float* ce_part = snP + 262144;          // 16*512
  float* nll_b = ce_part + 8192;          // 512
  float* l2_part = nll_b + 512;           // 128
  float* lp4 = l2_part + 128;             // 4*100*512 = 204800
  short* RbF = (short*)(lp4 + 204800);    // 4096 entries * 8 shorts
  short* nfB = RbF + 32768;               // 100*32*128*8 shorts

  float* out_prob = (float*)d_out;
  float* out4 = out_prob + (size_t)Bsz * Csz;

  prep_kernel<<<dim3(984), 256, 0, stream>>>(noise, nfB, rss, RbF, sqrtcov,
                                             X, W1, b1, h1, W2, W3, Wmu, l2_part,
                                             rsP, snP);

  gemm32<true><<<dim3(8, 16), 256, 0, stream>>>(h1, W2, b2, h2, 512, 256, 128);
  gemm32<true><<<dim3(8, 16), 256, 0, stream>>>(h2, W3, b3, feat, 512, 256, 256);
  gemm32_mu<<<dim3(16, 16), 256, 0, stream>>>(feat, Wmu, bmu, Y, sqrtcov,
                                              out_prob, rsP, snP, ce_part, 512, 500, 256);

  logprob_s3<<<dim3(3200), 256, 0, stream>>>(nfB, RbF, rsP, snP, lp4);
  nll_kernel<<<dim3(8), 256, 0, stream>>>(lp4, nll_b);

  finals_kernel<<<dim3(1), 256, 0, stream>>>(nll_b, ce_part, l2_part, 64, out4);
}